// Round 8
// baseline (490.058 us; speedup 1.0000x reference)
//
#include <hip/hip_runtime.h>
#include <hip/hip_bf16.h>

#define NA 4096
#define NP 49152

typedef _Float16 f16;
typedef _Float16 h2 __attribute__((ext_vector_type(2)));
union U4H { uint4 u; f16 h[8]; h2 p[4]; };

__device__ __forceinline__ float fdot2(h2 a, h2 b, float c){
#if __has_builtin(__builtin_amdgcn_fdot2)
  return __builtin_amdgcn_fdot2(a, b, c, false);
#else
  return c + (float)a.x*(float)b.x + (float)a.y*(float)b.y;
#endif
}

// ---------------- ws layout (float-element offsets) ----------------
constexpr int WS_Y     = 0;                    // 512*25 quadrature sph
constexpr int WS_G     = 12800;                // 5625 Gaunt tensor
constexpr int WS_NATT  = WS_G + 5632;          // int
constexpr int WS_ATTW  = WS_NATT + 8;          // 1024 floats
constexpr int WS_ATTIJ = WS_ATTW + 1024;       // 1024 ints, sorted by k (i-major inside)
constexpr int WS_TDOFS = WS_ATTIJ + 1024;      // 16 ints
constexpr int WS_TDW   = WS_TDOFS + 16;        // 512 floats
constexpr int WS_TDIJ  = WS_TDW + 512;         // 512 ints
constexpr int WS_AOFS  = WS_TDIJ + 512;        // 32 ints
constexpr int WS_SH    = WS_AOFS + 32;         // NP*9
constexpr int WS_RB    = WS_SH + NP*9;         // NP*16
constexpr int WS_S     = WS_RB + NP*16;        // NP scores (sorted index)
constexpr int WS_CCNT  = WS_S + NP;            // NA ints
constexpr int WS_COFF  = WS_CCNT + NA;         // NA+1 ints
constexpr int WS_CCUR  = WS_COFF + NA + 8;     // NA ints
constexpr int WS_CLST  = WS_CCUR + NA;         // NP ints (pair ids sorted by dst)
constexpr int WS_XA    = WS_CLST + NP;         // NA*400 f32 x
constexpr int WS_XQ    = WS_XA + NA*400;       // f16 transposed q; then agg f32
constexpr int WS_XK    = WS_XQ + NA*400;
constexpr int WS_XV    = WS_XK + NA*400;
constexpr int WS_PVF   = WS_XV + NA*400;       // f16 stream: NP*400 halves (att) / NP*144 (td)
// WW (95 species x {W1,W2} x 3d x 16k x 16g) lives in the PVF tail: only k_td
// reads it, and k_td's own PVF use is NP*144 halves = NP*72 f32 < this offset.
constexpr int WS_WW    = WS_PVF + NP*72;       // 145920 floats
constexpr long long WS_END = (long long)WS_PVF + (long long)NP*200;

__device__ const float  GLX[16] = {
  -0.98940093499164993f, -0.94457502307323258f, -0.86563120238783174f, -0.75540440835500303f,
  -0.61787624440264375f, -0.45801677765722739f, -0.28160355077925891f, -0.09501250983763744f,
   0.09501250983763744f,  0.28160355077925891f,  0.45801677765722739f,  0.61787624440264375f,
   0.75540440835500303f,  0.86563120238783174f,  0.94457502307323258f,  0.98940093499164993f };
__device__ const double GLW[16] = {
  0.02715245941175409, 0.06225352393864789, 0.09515851168249278, 0.12462897125553387,
  0.14959598881657673, 0.16915651939500254, 0.18260341504492359, 0.18945061045506850,
  0.18945061045506850, 0.18260341504492359, 0.16915651939500254, 0.14959598881657673,
  0.12462897125553387, 0.09515851168249278, 0.06225352393864789, 0.02715245941175409 };

#define PI_D 3.14159265358979323846

__device__ __forceinline__ float scrub(float v){
  if(!(v == v)) return 0.f;
  return fminf(fmaxf(v, -1e30f), 1e30f);
}

__device__ void real_sph25(float ct, float phi, float* Y){
  float st = sqrtf(fmaxf(0.f, 1.f - ct*ct));
  float P[5][5];
  P[0][0] = 1.f;
  #pragma unroll
  for(int m=1;m<=4;m++) P[m][m] = -(2.f*m - 1.f)*st*P[m-1][m-1];
  #pragma unroll
  for(int m=0;m<4;m++) P[m+1][m] = (2.f*m + 1.f)*ct*P[m][m];
  #pragma unroll
  for(int m=0;m<=4;m++){
    #pragma unroll
    for(int l=m+2;l<=4;l++)
      P[l][m] = ((2.f*l - 1.f)*ct*P[l-1][m] - (float)(l+m-1)*P[l-2][m]) / (float)(l-m);
  }
  const double fact[9] = {1,1,2,6,24,120,720,5040,40320};
  int idx = 0;
  #pragma unroll
  for(int l=0;l<=4;l++){
    #pragma unroll
    for(int m=-l;m<=l;m++){
      int ma = (m < 0) ? -m : m;
      float Nn = (float)sqrt((2*l+1)/(4.0*PI_D)*fact[l-ma]/fact[l+ma]);
      float cs = (ma & 1) ? -1.f : 1.f;
      float v;
      if(m == 0)      v = Nn * P[l][0];
      else if(m > 0)  v = 1.4142135623730951f * Nn * cs * cosf(ma*phi) * P[l][ma];
      else            v = 1.4142135623730951f * Nn * cs * sinf(ma*phi) * P[l][ma];
      Y[idx++] = v;
    }
  }
}

__global__ void kq_Y(float* ws){
  int g = blockIdx.x*256 + threadIdx.x;
  if(g >= 512) return;
  float ct  = GLX[g >> 5];
  float phi = (float)((g & 31) * (2.0*PI_D/32.0));
  float Y[25];
  real_sph25(ct, phi, Y);
  #pragma unroll
  for(int i=0;i<25;i++) ws[WS_Y + g*25 + i] = Y[i];
}

__global__ __launch_bounds__(256) void kq_G(float* ws){
  __shared__ float Ysh[12800];
  int tid = threadIdx.x;
  for(int t=tid; t<12800; t+=256) Ysh[t] = ws[WS_Y + t];
  __syncthreads();
  int t = blockIdx.x*256 + tid;
  if(t >= 5625) return;
  int k = t % 25, j = (t/25) % 9, i = t/225;
  double acc = 0.0;
  #pragma unroll 4
  for(int g=0; g<512; g++){
    double w = GLW[g >> 5] * (2.0*PI_D/32.0);
    acc += w * (double)Ysh[g*25+i] * (double)Ysh[g*25+j] * (double)Ysh[g*25+k];
  }
  if(fabs(acc) < 1e-6) acc = 0.0;
  ws[WS_G + (i*9+j)*25 + k] = (float)acc;
}

__global__ void kq_lists(float* ws){
  __shared__ int cA[25], cT[9], oA[26], oT[10];
  int t = threadIdx.x;
  const float* G = ws + WS_G;
  if(t < 25){ int c=0; for(int i=0;i<25;i++) for(int j=0;j<9;j++) if(G[(i*9+j)*25+t] != 0.f) c++; cA[t]=c; }
  if(t < 9){  int c=0; for(int i=0;i<9;i++)  for(int j=0;j<9;j++) if(G[(i*9+j)*25+t] != 0.f) c++; cT[t]=c; }
  __syncthreads();
  if(t == 0){
    int s=0; for(int k=0;k<25;k++){ oA[k]=s; s+=cA[k]; } oA[25]=s;
    ((int*)ws)[WS_NATT] = s;
    s=0; for(int k=0;k<9;k++){ oT[k]=s; s+=cT[k]; } oT[9]=s;
  }
  __syncthreads();
  float* attw = ws + WS_ATTW; int* attij = (int*)ws + WS_ATTIJ;
  int* aofs = (int*)ws + WS_AOFS;
  if(t < 26) aofs[t] = oA[t] < 1024 ? oA[t] : 1024;
  if(t < 25){
    int pos = oA[t];
    for(int i=0;i<25;i++) for(int j=0;j<9;j++){
      float w = G[(i*9+j)*25+t];
      if(w != 0.f && pos < 1024){ attw[pos]=w; attij[pos] = i | (j<<5) | (t<<9); pos++; }
    }
  }
  float* tdw = ws + WS_TDW; int* tdij = (int*)ws + WS_TDIJ; int* tdofs = (int*)ws + WS_TDOFS;
  if(t < 9){
    int pos = oT[t];
    for(int i=0;i<9;i++) for(int j=0;j<9;j++){
      float w = G[(i*9+j)*25+t];
      if(w != 0.f && pos < 512){
        int li = (i==0)?0:(i<4)?1:2, lj = (j==0)?0:(j<4)?1:2;
        tdw[pos]=w; tdij[pos] = i | (j<<5) | (li<<10) | (lj<<12); pos++;
      }
    }
    tdofs[t] = oT[t];
    if(t == 0) tdofs[9] = oT[9];
  }
}

__global__ void k_pair(const float* disp, float* ws){
  int p = blockIdx.x*256 + threadIdx.x;
  if(p >= NP) return;
  float dx = disp[3*p], dy = disp[3*p+1], dz = disp[3*p+2];
  float r = sqrtf(dx*dx + dy*dy + dz*dz);
  float inv = 1.f / fmaxf(r, 1e-9f);
  float ux = dx*inv, uy = dy*inv, uz = dz*inv;
  float sh[9];
  sh[0] = 0.28209479177387814f;
  sh[1] = 0.4886025119029199f * uy;
  sh[2] = 0.4886025119029199f * uz;
  sh[3] = 0.4886025119029199f * ux;
  sh[4] = 1.0925484305920792f * ux*uy;
  sh[5] = 1.0925484305920792f * uy*uz;
  sh[6] = 0.31539156525252005f * (3.f*uz*uz - 1.f);
  sh[7] = 1.0925484305920792f * ux*uz;
  sh[8] = 0.5462742152960396f * (ux*ux - uy*uy);
  #pragma unroll
  for(int i=0;i<9;i++) ws[WS_SH + p*9 + i] = scrub(sh[i]);
  float mask = (r < 5.f) ? 1.f : 0.f;
  #pragma unroll
  for(int k=1;k<=16;k++){
    float x  = (float)k * r * 0.2f;
    float px = 3.14159265358979323846f * x;
    float s  = (px < 1e-6f) ? 1.f : (sinf(px)/px);
    ws[WS_RB + p*16 + (k-1)] = scrub(s * mask);
  }
}

// ---------------- CSR by dst ----------------
__global__ void k_cnt(const int* nbr, float* ws){
  int p = blockIdx.x*256 + threadIdx.x;
  if(p >= NP) return;
  atomicAdd((int*)ws + WS_CCNT + nbr[2*p], 1);
}

__global__ __launch_bounds__(1024) void k_scan(float* ws){
  __shared__ int part[1024];
  int t = threadIdx.x;
  const int* cnt = (const int*)ws + WS_CCNT;
  int v0 = cnt[4*t], v1 = cnt[4*t+1], v2 = cnt[4*t+2], v3 = cnt[4*t+3];
  part[t] = v0+v1+v2+v3;
  __syncthreads();
  for(int o=1; o<1024; o<<=1){
    int x = (t >= o) ? part[t-o] : 0;
    __syncthreads();
    part[t] += x;
    __syncthreads();
  }
  int base = (t > 0) ? part[t-1] : 0;
  int* offp = (int*)ws + WS_COFF;
  int* cur  = (int*)ws + WS_CCUR;
  offp[4*t]   = base;          cur[4*t]   = base;
  offp[4*t+1] = base+v0;       cur[4*t+1] = base+v0;
  offp[4*t+2] = base+v0+v1;    cur[4*t+2] = base+v0+v1;
  offp[4*t+3] = base+v0+v1+v2; cur[4*t+3] = base+v0+v1+v2;
  if(t == 1023) offp[4096] = part[1023];
}

__global__ void k_fill(const int* nbr, float* ws){
  int p = blockIdx.x*256 + threadIdx.x;
  if(p >= NP) return;
  int d = nbr[2*p];
  int pos = atomicAdd((int*)ws + WS_CCUR + d, 1);
  ((int*)ws)[WS_CLST + pos] = p;
}

// ---------------- WW prefold: WW[s][w][d][k][g] = sum_fp Wrad*W{1,2} -------
__global__ __launch_bounds__(256) void k_ww(const float* Wrad, const float* W1,
                                            const float* W2, float* ws){
  int s = blockIdx.x;
  #pragma unroll
  for(int it=0; it<6; it++){
    int idx = threadIdx.x + 256*it;
    int w = idx / 768, r = idx % 768;
    int d = r / 256, r2 = r % 256, k = r2 / 16, g = r2 % 16;
    const float* Wsrc = (w == 0) ? W1 : W2;
    float acc = 0.f;
    #pragma unroll
    for(int fp=0; fp<16; fp++)
      acc += Wrad[(s*16+k)*16+fp] * Wsrc[(d*16+fp)*16+g];
    ws[WS_WW + ((size_t)(s*2+w)*16 + g)*48 + d*16 + k] = acc;
  }
}

// ---------------- TD phase: WW-folded A, S-matrix Gaunt, streams f16 -------
__global__ __launch_bounds__(256) void k_td(const int* aZ, const int* nbr,
    const float* W3, float* ws){
  __shared__ float sh_s[16][9];
  __shared__ float S_s[16][88];      // [pair][k*9 + li*3+lj], 81 used
  __shared__ float tp_s[16][9][16];
  int tid = threadIdx.x, pl = tid >> 4, g = tid & 15;
  int sp = blockIdx.x*16 + pl;
  int p = ((const int*)ws)[WS_CLST + sp];
  int src = nbr[2*p+1];
  int Zj = aZ[src];
  // zero S
  {
    float4* S4 = (float4*)&S_s[0][0];
    for(int t0=tid; t0<352; t0+=256) S4[t0] = make_float4(0.f,0.f,0.f,0.f);
  }
  if(g < 9) sh_s[pl][g] = ws[WS_SH + p*9 + g];
  // rb (4 x float4) and A via WW (24 x float4 + 96 fma)
  float rb[16];
  {
    const float4* rb4 = (const float4*)(ws + WS_RB + p*16);
    #pragma unroll
    for(int c=0;c<4;c++){
      float4 r = rb4[c];
      rb[4*c]=r.x; rb[4*c+1]=r.y; rb[4*c+2]=r.z; rb[4*c+3]=r.w;
    }
  }
  float A1[3], A2[3];
  {
    const float4* w1 = (const float4*)(ws + WS_WW + ((size_t)(Zj*2+0)*16+g)*48);
    const float4* w2 = (const float4*)(ws + WS_WW + ((size_t)(Zj*2+1)*16+g)*48);
    #pragma unroll
    for(int d=0; d<3; d++){
      float a1 = 0.f, a2 = 0.f;
      #pragma unroll
      for(int c=0;c<4;c++){
        float4 x1 = w1[d*4+c], x2 = w2[d*4+c];
        a1 += x1.x*rb[4*c] + x1.y*rb[4*c+1] + x1.z*rb[4*c+2] + x1.w*rb[4*c+3];
        a2 += x2.x*rb[4*c] + x2.y*rb[4*c+1] + x2.z*rb[4*c+2] + x2.w*rb[4*c+3];
      }
      A1[d] = a1; A2[d] = a2;
    }
  }
  __syncthreads();
  // S build: lane g (<9) owns td k-row g
  if(g < 9){
    const float* tdw = ws + WS_TDW;
    const int* tdij  = (const int*)ws + WS_TDIJ;
    const int* tdofs = (const int*)ws + WS_TDOFS;
    int e1 = tdofs[g+1];
    for(int e=tdofs[g]; e<e1; e++){
      float w = tdw[e]; int meta = tdij[e];
      int i = meta & 31, j = (meta>>5) & 15, li = (meta>>10) & 3, lj = (meta>>12) & 3;
      S_s[pl][g*9 + li*3 + lj] += w * sh_s[pl][i] * sh_s[pl][j];
    }
  }
  __syncthreads();
  float AA[9];
  #pragma unroll
  for(int li=0;li<3;li++)
    #pragma unroll
    for(int lj=0;lj<3;lj++) AA[li*3+lj] = A1[li]*A2[lj];
  #pragma unroll
  for(int k=0;k<9;k++){
    float tpv = 0.f;
    #pragma unroll
    for(int c=0;c<9;c++) tpv += S_s[pl][k*9+c] * AA[c];
    tp_s[pl][k][g] = tpv;
  }
  __syncthreads();
  // W3 stage (preloaded weights), stream f16 at sorted index
  float w3r[48];
  #pragma unroll
  for(int d=0;d<3;d++)
    #pragma unroll
    for(int f2=0;f2<16;f2++) w3r[d*16+f2] = W3[(d*16+f2)*16+g];
  f16* ptd = (f16*)(ws + WS_PVF);
  #pragma unroll
  for(int k=0;k<9;k++){
    int d = (k==0)?0:(k<4)?1:2;
    const float4* t4 = (const float4*)&tp_s[pl][k][0];
    float acc = 0.f;
    #pragma unroll
    for(int c=0;c<4;c++){
      float4 t = t4[c];
      acc += t.x*w3r[d*16+4*c] + t.y*w3r[d*16+4*c+1] + t.z*w3r[d*16+4*c+2] + t.w*w3r[d*16+4*c+3];
    }
    ptd[(size_t)sp*144 + k*16 + g] = (f16)scrub(acc);
  }
}

// ---------------- TD gather: mean over contiguous f16 rows -----------------
__global__ __launch_bounds__(256) void k_tdgather(float* ws){
  int a = blockIdx.x*4 + (threadIdx.x >> 6);
  int lane = threadIdx.x & 63;
  const int* coff = (const int*)ws + WS_COFF;
  int off0 = coff[a], n = coff[a+1] - off0;
  float acc[8] = {0,0,0,0,0,0,0,0};
  const f16* base = (const f16*)(ws + WS_PVF);
  for(int t=0; t<n; t++){
    if(lane < 18){
      U4H u; u.u = *(const uint4*)(base + (size_t)(off0+t)*144 + lane*8);
      #pragma unroll
      for(int j=0;j<8;j++) acc[j] += (float)u.h[j];
    }
  }
  float invn = 1.f / fmaxf((float)n, 1.f);
  float* xa = ws + WS_XA + a*400;
  if(lane < 18){
    #pragma unroll
    for(int j=0;j<8;j++) xa[lane*8 + j] = scrub(acc[j]*invn);
  }
  #pragma unroll
  for(int j=0;j<4;j++) xa[144 + j*64 + lane] = 0.f;
}

// ---------------- Q/K/V pdense -> f16 transposed (stride 32 halves) --------
template<int NL>
__global__ __launch_bounds__(256) void k_qkv(const float* Wq,
    const float* Wk, const float* Wv, float* ws){
  int tid = threadIdx.x, al = tid >> 4, g = tid & 15;
  int a = blockIdx.x*16 + al;
  const float* x = ws + WS_XA + a*400;
  constexpr int NR = NL*NL;
  float q_r[NR], k_r[NR], v_r[NR];
  int i = 0;
  #pragma unroll
  for(int l=0;l<NL;l++){
    float wq[16], wk[16], wv[16];
    #pragma unroll
    for(int f2=0;f2<16;f2++){
      wq[f2] = Wq[(l*16+f2)*16+g];
      wk[f2] = Wk[(l*16+f2)*16+g];
      wv[f2] = Wv[(l*16+f2)*16+g];
    }
    for(int mi=0; mi<2*l+1; mi++, i++){
      float q=0.f, k2=0.f, v2=0.f;
      #pragma unroll
      for(int f2=0;f2<16;f2++){
        float xv = x[i*16+f2];
        q += xv*wq[f2]; k2 += xv*wk[f2]; v2 += xv*wv[f2];
      }
      q_r[i]=q; k_r[i]=k2; v_r[i]=v2;
    }
  }
  f16* qt = (f16*)(ws + WS_XQ) + (size_t)a*800 + g*32;
  f16* kt = (f16*)(ws + WS_XK) + (size_t)a*800 + g*32;
  f16* vt = (f16*)(ws + WS_XV) + (size_t)a*800 + g*32;
  #pragma unroll
  for(int c=0;c<NR/8;c++){
    U4H uq, uk, uv;
    #pragma unroll
    for(int j=0;j<4;j++){
      h2 tq, tk, tv;
      tq.x=(f16)q_r[c*8+2*j]; tq.y=(f16)q_r[c*8+2*j+1];
      tk.x=(f16)k_r[c*8+2*j]; tk.y=(f16)k_r[c*8+2*j+1];
      tv.x=(f16)v_r[c*8+2*j]; tv.y=(f16)v_r[c*8+2*j+1];
      uq.p[j]=tq; uk.p[j]=tk; uv.p[j]=tv;
    }
    *(uint4*)(qt + c*8) = uq.u;
    *(uint4*)(kt + c*8) = uk.u;
    *(uint4*)(vt + c*8) = uv.u;
  }
  qt[NR-1] = (f16)q_r[NR-1];
  kt[NR-1] = (f16)k_r[NR-1];
  vt[NR-1] = (f16)v_r[NR-1];
}

// ---------------- merged attention, f16 M in LDS (b128 sweep) --------------
// NI = nonzero x rows (9 layer1, 25 layer2). Processes SORTED pair sp.
template<int NI>
__global__ __launch_bounds__(128) void k_att(const int* nbr, const float* Wb, float* ws){
  __shared__ __align__(16) f16 Ml[8][840];   // row stride 32, pl stride 840 (bank spread)
  __shared__ float sh_s[8][9];
  constexpr int NPAIR = NI/2;        // 12 or 4
  constexpr int TAIL  = NI-1;        // 24 or 8
  int tid = threadIdx.x, pl = tid >> 4, g = tid & 15;
  int sp = blockIdx.x*8 + pl;
  int p = ((const int*)ws)[WS_CLST + sp];
  // zero M: 8*840 halves = 840 uint4
  {
    uint4 z; z.x=0; z.y=0; z.z=0; z.w=0;
    uint4* Mz = (uint4*)&Ml[0][0];
    for(int t0=tid; t0<840; t0+=128) Mz[t0] = z;
  }
  if(g < 9) sh_s[pl][g] = ws[WS_SH + p*9 + g];
  // block-invariant Wb row (per lane g)
  float wbreg[16];
  #pragma unroll
  for(int k=0;k<16;k++) wbreg[k] = Wb[k*16+g];
  __syncthreads();
  // run-length f16 M build (entries per row k sorted by i)
  {
    const float* attw = ws + WS_ATTW;
    const int* attij  = (const int*)ws + WS_ATTIJ;
    const int* aofs   = (const int*)ws + WS_AOFS;
    for(int kr=g; kr<25; kr+=16){
      f16* Mrow = &Ml[pl][kr*32];
      int e = aofs[kr], e1 = aofs[kr+1];
      int meta = attij[e];
      int curi = meta & 31;
      float cur = 0.f;
      for(; e<e1; e++){
        meta = attij[e];
        int i2 = meta & 31;
        if(i2 != curi){ Mrow[curi] = (f16)cur; cur = 0.f; curi = i2; }
        cur += attw[e] * sh_s[pl][(meta>>5) & 15];
      }
      Mrow[curi] = (f16)cur;
    }
  }
  __syncthreads();
  int dst = nbr[2*p], src = nbr[2*p+1];
  // q (f32 from f16 transposed row)
  float q_r[NI];
  {
    const f16* qt = (const f16*)(ws + WS_XQ) + (size_t)dst*800 + g*32;
    #pragma unroll
    for(int c=0;c<NPAIR/4;c++){
      U4H u; u.u = *(const uint4*)(qt + c*8);
      #pragma unroll
      for(int j=0;j<8;j++) q_r[c*8+j] = (float)u.h[j];
    }
    q_r[TAIL] = (float)qt[TAIL];
  }
  // k,v packed half2
  h2 xk2[NPAIR], xv2[NPAIR];
  float xkT, xvT;
  {
    const f16* kt = (const f16*)(ws + WS_XK) + (size_t)src*800 + g*32;
    const f16* vt = (const f16*)(ws + WS_XV) + (size_t)src*800 + g*32;
    #pragma unroll
    for(int c=0;c<NPAIR/4;c++){
      U4H uk; uk.u = *(const uint4*)(kt + c*8);
      U4H uv; uv.u = *(const uint4*)(vt + c*8);
      #pragma unroll
      for(int j=0;j<4;j++){ xk2[c*4+j] = uk.p[j]; xv2[c*4+j] = uv.p[j]; }
    }
    xkT = (float)kt[TAIL];
    xvT = (float)vt[TAIL];
  }
  // wbf via float4 rb + preloaded Wb (no shuffles)
  float wbf;
  {
    const float4* rb4 = (const float4*)(ws + WS_RB + p*16);
    float acc = 0.f;
    #pragma unroll
    for(int c=0;c<4;c++){
      float4 r = rb4[c];
      acc += r.x*wbreg[4*c] + r.y*wbreg[4*c+1] + r.z*wbreg[4*c+2] + r.w*wbreg[4*c+3];
    }
    wbf = acc;
  }
  f16* pvf = (f16*)(ws + WS_PVF) + (size_t)sp*400;
  float sacc = 0.f;
  #pragma unroll
  for(int k=0;k<25;k++){
    const uint4* Mq = (const uint4*)&Ml[pl][k*32];
    float mT = (float)Ml[pl][k*32 + TAIL];
    float vv = 0.f, kf = 0.f;
    #pragma unroll
    for(int c=0;c<NPAIR/4;c++){
      U4H u; u.u = Mq[c];
      #pragma unroll
      for(int j=0;j<4;j++){
        vv = fdot2(u.p[j], xv2[c*4+j], vv);
        if(k < NI) kf = fdot2(u.p[j], xk2[c*4+j], kf);
      }
    }
    vv += mT * xvT;
    if(k < NI){
      kf += mT * xkT;
      sacc += q_r[k]*kf;
    }
    pvf[k*16 + g] = (f16)scrub(wbf*vv);
  }
  float sl = wbf * sacc;
  #pragma unroll
  for(int off=1; off<16; off<<=1) sl += __shfl_xor(sl, off, 16);
  if(g == 0) ws[WS_S + sp] = scrub(sl * 0.05f);   // / sqrt(25*16)
}

// ---------------- gather: softmax + alpha-weighted contiguous reduce -------
__global__ __launch_bounds__(256) void k_aggather(float* ws){
  int a = blockIdx.x*4 + (threadIdx.x >> 6);
  int lane = threadIdx.x & 63;
  const int* coff = (const int*)ws + WS_COFF;
  int off0 = coff[a], n = coff[a+1] - off0;
  float mx = -1e30f;
  for(int t=lane; t<n; t+=64) mx = fmaxf(mx, ws[WS_S + off0 + t]);
  #pragma unroll
  for(int off=1; off<64; off<<=1) mx = fmaxf(mx, __shfl_xor(mx, off));
  float den = 0.f;
  for(int t=lane; t<n; t+=64) den += expf(fminf(ws[WS_S + off0 + t] - mx, 0.f));
  #pragma unroll
  for(int off=1; off<64; off<<=1) den += __shfl_xor(den, off);
  float inv_den = 1.f / (den + 1e-9f);
  float acc[8] = {0,0,0,0,0,0,0,0};
  const f16* base = (const f16*)(ws + WS_PVF);
  for(int t=0; t<n; t++){
    float alpha = expf(fminf(ws[WS_S + off0 + t] - mx, 0.f)) * inv_den;
    if(lane < 50){
      U4H u; u.u = *(const uint4*)(base + (size_t)(off0+t)*400 + lane*8);
      #pragma unroll
      for(int j=0;j<8;j++) acc[j] += alpha * (float)u.h[j];
    }
  }
  if(lane < 50){
    float* agg = ws + WS_XQ + a*400 + lane*8;
    #pragma unroll
    for(int j=0;j<8;j++) agg[j] = scrub(acc[j]);
  }
}

// ---------------- output pdense + bias; FINAL adds residual ----------------
template<bool FINAL>
__global__ __launch_bounds__(256) void k_o(const float* Wo, const float* bo,
    const int* aZ, const float* emb, const float* Wemb, const float* bemb,
    float* ws, float* out){
  int tid = threadIdx.x, al = tid >> 4, g = tid & 15;
  int a = blockIdx.x*16 + al;
  const float* agg = ws + WS_XQ + a*400;
  int i = 0;
  #pragma unroll
  for(int l=0;l<5;l++){
    float wo[16];
    #pragma unroll
    for(int f2=0;f2<16;f2++) wo[f2] = Wo[(l*16+f2)*16+g];
    for(int mi=0; mi<2*l+1; mi++, i++){
      float acc = 0.f;
      #pragma unroll
      for(int f2=0;f2<16;f2++) acc += agg[i*16+f2]*wo[f2];
      if(i == 0){
        acc += bo[g];
        if(FINAL){
          int Z = aZ[a];
          float res = bemb[g];
          #pragma unroll
          for(int e2=0;e2<32;e2++) res += emb[Z*32+e2] * Wemb[e2*16+g];
          acc += res;
        }
      }
      if(FINAL) out[a*400 + i*16 + g] = scrub(acc);
      else      ws[WS_XA + a*400 + i*16 + g] = scrub(acc);
    }
  }
}

extern "C" void kernel_launch(void* const* d_in, const int* in_sizes, int n_in,
                              void* d_out, int out_size, void* d_ws, size_t ws_size,
                              hipStream_t stream){
  (void)in_sizes; (void)n_in; (void)out_size;
  if(ws_size < (size_t)WS_END * sizeof(float)) return;
  float* ws = (float*)d_ws;
  const int* aZ  = (const int*)d_in[0];
  const int* nbr = (const int*)d_in[1];
  const float* disp = (const float*)d_in[2];
  const float* Wrad = (const float*)d_in[3];
  const float* emb  = (const float*)d_in[4];
  const float* Wemb = (const float*)d_in[5];
  const float* bemb = (const float*)d_in[6];
  const float* W1   = (const float*)d_in[7];
  const float* W2   = (const float*)d_in[8];
  const float* W3   = (const float*)d_in[9];

  kq_Y<<<2,256,0,stream>>>(ws);
  kq_G<<<22,256,0,stream>>>(ws);
  kq_lists<<<1,64,0,stream>>>(ws);
  k_pair<<<192,256,0,stream>>>(disp, ws);
  hipMemsetAsync(ws + WS_CCNT, 0, NA*sizeof(int), stream);
  k_cnt<<<192,256,0,stream>>>(nbr, ws);
  k_scan<<<1,1024,0,stream>>>(ws);
  k_fill<<<192,256,0,stream>>>(nbr, ws);
  k_ww<<<95,256,0,stream>>>(Wrad, W1, W2, ws);
  k_td<<<3072,256,0,stream>>>(aZ, nbr, W3, ws);
  k_tdgather<<<1024,256,0,stream>>>(ws);

  for(int l=0;l<2;l++){
    const float* Wb = (const float*)d_in[10+6*l];
    const float* Wq = (const float*)d_in[11+6*l];
    const float* Wk = (const float*)d_in[12+6*l];
    const float* Wv = (const float*)d_in[13+6*l];
    const float* Wo = (const float*)d_in[14+6*l];
    const float* bo = (const float*)d_in[15+6*l];
    if(l == 0){
      k_qkv<3><<<256,256,0,stream>>>(Wq, Wk, Wv, ws);
      k_att<9><<<6144,128,0,stream>>>(nbr, Wb, ws);
    } else {
      k_qkv<5><<<256,256,0,stream>>>(Wq, Wk, Wv, ws);
      k_att<25><<<6144,128,0,stream>>>(nbr, Wb, ws);
    }
    k_aggather<<<1024,256,0,stream>>>(ws);
    if(l == 0) k_o<false><<<256,256,0,stream>>>(Wo, bo, aZ, emb, Wemb, bemb, ws, nullptr);
    else       k_o<true ><<<256,256,0,stream>>>(Wo, bo, aZ, emb, Wemb, bemb, ws, (float*)d_out);
  }
}

// Round 9
// 483.760 us; speedup vs baseline: 1.0130x; 1.0130x over previous
//
#include <hip/hip_runtime.h>
#include <hip/hip_bf16.h>

#define NA 4096
#define NP 49152

typedef _Float16 f16;
typedef _Float16 h2 __attribute__((ext_vector_type(2)));
union U4H { uint4 u; f16 h[8]; h2 p[4]; };

__device__ __forceinline__ float fdot2(h2 a, h2 b, float c){
#if __has_builtin(__builtin_amdgcn_fdot2)
  return __builtin_amdgcn_fdot2(a, b, c, false);
#else
  return c + (float)a.x*(float)b.x + (float)a.y*(float)b.y;
#endif
}

// ---------------- ws layout (float-element offsets) ----------------
constexpr int WS_Y     = 0;                    // (unused, kept for layout)
constexpr int WS_G     = 12800;                // 5625 Gaunt tensor
constexpr int WS_NATT  = WS_G + 5632;          // int
constexpr int WS_ATTW  = WS_NATT + 8;          // 1024 floats
constexpr int WS_ATTIJ = WS_ATTW + 1024;       // 1024 ints, sorted by k (i-major inside)
constexpr int WS_TDOFS = WS_ATTIJ + 1024;      // 16 ints
constexpr int WS_TDW   = WS_TDOFS + 16;        // 512 floats
constexpr int WS_TDIJ  = WS_TDW + 512;         // 512 ints
constexpr int WS_AOFS  = WS_TDIJ + 512;        // 32 ints
constexpr int WS_SH    = WS_AOFS + 32;         // NP*9
constexpr int WS_RB    = WS_SH + NP*9;         // NP*16
constexpr int WS_S     = WS_RB + NP*16;        // NP scores (sorted index)
constexpr int WS_CCNT  = WS_S + NP;            // NA ints
constexpr int WS_COFF  = WS_CCNT + NA;         // NA+1 ints
constexpr int WS_CCUR  = WS_COFF + NA + 8;     // NA ints
constexpr int WS_CLST  = WS_CCUR + NA;         // NP ints (pair ids sorted by dst)
constexpr int WS_XQ    = WS_CLST + NP;         // f16 transposed q (NA*800 halves)
constexpr int WS_XK    = WS_XQ + NA*400;
constexpr int WS_XV    = WS_XK + NA*400;
constexpr int WS_PVF   = WS_XV + NA*400;       // f16 stream: att [sp][g][32] (NP*512 halves)
                                               //             td  [sp][g][16] (NP*256 halves)
constexpr int WS_WW    = WS_PVF + NP*128;      // 145920 floats (dead after k_td)
constexpr long long WS_END = (long long)WS_PVF + (long long)NP*256;  // ~76 MB

__device__ const float  GLX[16] = {
  -0.98940093499164993f, -0.94457502307323258f, -0.86563120238783174f, -0.75540440835500303f,
  -0.61787624440264375f, -0.45801677765722739f, -0.28160355077925891f, -0.09501250983763744f,
   0.09501250983763744f,  0.28160355077925891f,  0.45801677765722739f,  0.61787624440264375f,
   0.75540440835500303f,  0.86563120238783174f,  0.94457502307323258f,  0.98940093499164993f };
__device__ const double GLW[16] = {
  0.02715245941175409, 0.06225352393864789, 0.09515851168249278, 0.12462897125553387,
  0.14959598881657673, 0.16915651939500254, 0.18260341504492359, 0.18945061045506850,
  0.18945061045506850, 0.18260341504492359, 0.16915651939500254, 0.14959598881657673,
  0.12462897125553387, 0.09515851168249278, 0.06225352393864789, 0.02715245941175409 };

#define PI_D 3.14159265358979323846

__device__ __forceinline__ float scrub(float v){
  if(!(v == v)) return 0.f;
  return fminf(fmaxf(v, -1e30f), 1e30f);
}

__device__ void real_sph25(float ct, float phi, float* Y){
  float st = sqrtf(fmaxf(0.f, 1.f - ct*ct));
  float P[5][5];
  P[0][0] = 1.f;
  #pragma unroll
  for(int m=1;m<=4;m++) P[m][m] = -(2.f*m - 1.f)*st*P[m-1][m-1];
  #pragma unroll
  for(int m=0;m<4;m++) P[m+1][m] = (2.f*m + 1.f)*ct*P[m][m];
  #pragma unroll
  for(int m=0;m<=4;m++){
    #pragma unroll
    for(int l=m+2;l<=4;l++)
      P[l][m] = ((2.f*l - 1.f)*ct*P[l-1][m] - (float)(l+m-1)*P[l-2][m]) / (float)(l-m);
  }
  const double fact[9] = {1,1,2,6,24,120,720,5040,40320};
  int idx = 0;
  #pragma unroll
  for(int l=0;l<=4;l++){
    #pragma unroll
    for(int m=-l;m<=l;m++){
      int ma = (m < 0) ? -m : m;
      float Nn = (float)sqrt((2*l+1)/(4.0*PI_D)*fact[l-ma]/fact[l+ma]);
      float cs = (ma & 1) ? -1.f : 1.f;
      float v;
      if(m == 0)      v = Nn * P[l][0];
      else if(m > 0)  v = 1.4142135623730951f * Nn * cs * cosf(ma*phi) * P[l][ma];
      else            v = 1.4142135623730951f * Nn * cs * sinf(ma*phi) * P[l][ma];
      Y[idx++] = v;
    }
  }
}

// G kernel with in-block Y recompute (kq_Y folded in)
__global__ __launch_bounds__(256) void kq_G(float* ws){
  __shared__ float Ysh[12800];
  int tid = threadIdx.x;
  for(int pt=tid; pt<512; pt+=256){
    float ct  = GLX[pt >> 5];
    float phi = (float)((pt & 31) * (2.0*PI_D/32.0));
    float Y[25];
    real_sph25(ct, phi, Y);
    #pragma unroll
    for(int i=0;i<25;i++) Ysh[pt*25 + i] = Y[i];
  }
  __syncthreads();
  int t = blockIdx.x*256 + tid;
  if(t >= 5625) return;
  int k = t % 25, j = (t/25) % 9, i = t/225;
  double acc = 0.0;
  #pragma unroll 4
  for(int g=0; g<512; g++){
    double w = GLW[g >> 5] * (2.0*PI_D/32.0);
    acc += w * (double)Ysh[g*25+i] * (double)Ysh[g*25+j] * (double)Ysh[g*25+k];
  }
  if(fabs(acc) < 1e-6) acc = 0.0;
  ws[WS_G + (i*9+j)*25 + k] = (float)acc;
}

__global__ void kq_lists(float* ws){
  __shared__ int cA[25], cT[9], oA[26], oT[10];
  int t = threadIdx.x;
  const float* G = ws + WS_G;
  if(t < 25){ int c=0; for(int i=0;i<25;i++) for(int j=0;j<9;j++) if(G[(i*9+j)*25+t] != 0.f) c++; cA[t]=c; }
  if(t < 9){  int c=0; for(int i=0;i<9;i++)  for(int j=0;j<9;j++) if(G[(i*9+j)*25+t] != 0.f) c++; cT[t]=c; }
  __syncthreads();
  if(t == 0){
    int s=0; for(int k=0;k<25;k++){ oA[k]=s; s+=cA[k]; } oA[25]=s;
    ((int*)ws)[WS_NATT] = s;
    s=0; for(int k=0;k<9;k++){ oT[k]=s; s+=cT[k]; } oT[9]=s;
  }
  __syncthreads();
  float* attw = ws + WS_ATTW; int* attij = (int*)ws + WS_ATTIJ;
  int* aofs = (int*)ws + WS_AOFS;
  if(t < 26) aofs[t] = oA[t] < 1024 ? oA[t] : 1024;
  if(t < 25){
    int pos = oA[t];
    for(int i=0;i<25;i++) for(int j=0;j<9;j++){
      float w = G[(i*9+j)*25+t];
      if(w != 0.f && pos < 1024){ attw[pos]=w; attij[pos] = i | (j<<5) | (t<<9); pos++; }
    }
  }
  float* tdw = ws + WS_TDW; int* tdij = (int*)ws + WS_TDIJ; int* tdofs = (int*)ws + WS_TDOFS;
  if(t < 9){
    int pos = oT[t];
    for(int i=0;i<9;i++) for(int j=0;j<9;j++){
      float w = G[(i*9+j)*25+t];
      if(w != 0.f && pos < 512){
        int li = (i==0)?0:(i<4)?1:2, lj = (j==0)?0:(j<4)?1:2;
        tdw[pos]=w; tdij[pos] = i | (j<<5) | (li<<10) | (lj<<12); pos++;
      }
    }
    tdofs[t] = oT[t];
    if(t == 0) tdofs[9] = oT[9];
  }
}

__global__ void k_pair(const float* disp, float* ws){
  int p = blockIdx.x*256 + threadIdx.x;
  if(p >= NP) return;
  float dx = disp[3*p], dy = disp[3*p+1], dz = disp[3*p+2];
  float r = sqrtf(dx*dx + dy*dy + dz*dz);
  float inv = 1.f / fmaxf(r, 1e-9f);
  float ux = dx*inv, uy = dy*inv, uz = dz*inv;
  float sh[9];
  sh[0] = 0.28209479177387814f;
  sh[1] = 0.4886025119029199f * uy;
  sh[2] = 0.4886025119029199f * uz;
  sh[3] = 0.4886025119029199f * ux;
  sh[4] = 1.0925484305920792f * ux*uy;
  sh[5] = 1.0925484305920792f * uy*uz;
  sh[6] = 0.31539156525252005f * (3.f*uz*uz - 1.f);
  sh[7] = 1.0925484305920792f * ux*uz;
  sh[8] = 0.5462742152960396f * (ux*ux - uy*uy);
  #pragma unroll
  for(int i=0;i<9;i++) ws[WS_SH + p*9 + i] = scrub(sh[i]);
  float mask = (r < 5.f) ? 1.f : 0.f;
  #pragma unroll
  for(int k=1;k<=16;k++){
    float x  = (float)k * r * 0.2f;
    float px = 3.14159265358979323846f * x;
    float s  = (px < 1e-6f) ? 1.f : (sinf(px)/px);
    ws[WS_RB + p*16 + (k-1)] = scrub(s * mask);
  }
}

// ---------------- CSR by dst ----------------
__global__ void k_cnt(const int* nbr, float* ws){
  int p = blockIdx.x*256 + threadIdx.x;
  if(p >= NP) return;
  atomicAdd((int*)ws + WS_CCNT + nbr[2*p], 1);
}

__global__ __launch_bounds__(1024) void k_scan(float* ws){
  __shared__ int part[1024];
  int t = threadIdx.x;
  const int* cnt = (const int*)ws + WS_CCNT;
  int v0 = cnt[4*t], v1 = cnt[4*t+1], v2 = cnt[4*t+2], v3 = cnt[4*t+3];
  part[t] = v0+v1+v2+v3;
  __syncthreads();
  for(int o=1; o<1024; o<<=1){
    int x = (t >= o) ? part[t-o] : 0;
    __syncthreads();
    part[t] += x;
    __syncthreads();
  }
  int base = (t > 0) ? part[t-1] : 0;
  int* offp = (int*)ws + WS_COFF;
  int* cur  = (int*)ws + WS_CCUR;
  offp[4*t]   = base;          cur[4*t]   = base;
  offp[4*t+1] = base+v0;       cur[4*t+1] = base+v0;
  offp[4*t+2] = base+v0+v1;    cur[4*t+2] = base+v0+v1;
  offp[4*t+3] = base+v0+v1+v2; cur[4*t+3] = base+v0+v1+v2;
  if(t == 1023) offp[4096] = part[1023];
}

__global__ void k_fill(const int* nbr, float* ws){
  int p = blockIdx.x*256 + threadIdx.x;
  if(p >= NP) return;
  int d = nbr[2*p];
  int pos = atomicAdd((int*)ws + WS_CCUR + d, 1);
  ((int*)ws)[WS_CLST + pos] = p;
}

// ---------------- WW prefold: WW[s][w][g][d][k] ----------------
__global__ __launch_bounds__(256) void k_ww(const float* Wrad, const float* W1,
                                            const float* W2, float* ws){
  int s = blockIdx.x;
  #pragma unroll
  for(int it=0; it<6; it++){
    int idx = threadIdx.x + 256*it;
    int w = idx / 768, r = idx % 768;
    int d = r / 256, r2 = r % 256, k = r2 / 16, g = r2 % 16;
    const float* Wsrc = (w == 0) ? W1 : W2;
    float acc = 0.f;
    #pragma unroll
    for(int fp=0; fp<16; fp++)
      acc += Wrad[(s*16+k)*16+fp] * Wsrc[(d*16+fp)*16+g];
    ws[WS_WW + ((size_t)(s*2+w)*16 + g)*48 + d*16 + k] = acc;
  }
}

// ---------------- TD phase: WW-folded A, S-matrix Gaunt, wide f16 stores ---
__global__ __launch_bounds__(256) void k_td(const int* aZ, const int* nbr,
    const float* W3, float* ws){
  __shared__ float sh_s[16][9];
  __shared__ float S_s[16][88];
  __shared__ float tp_s[16][9][16];
  int tid = threadIdx.x, pl = tid >> 4, g = tid & 15;
  int sp = blockIdx.x*16 + pl;
  int p = ((const int*)ws)[WS_CLST + sp];
  int src = nbr[2*p+1];
  int Zj = aZ[src];
  {
    float4* S4 = (float4*)&S_s[0][0];
    for(int t0=tid; t0<352; t0+=256) S4[t0] = make_float4(0.f,0.f,0.f,0.f);
  }
  if(g < 9) sh_s[pl][g] = ws[WS_SH + p*9 + g];
  float rb[16];
  {
    const float4* rb4 = (const float4*)(ws + WS_RB + p*16);
    #pragma unroll
    for(int c=0;c<4;c++){
      float4 r = rb4[c];
      rb[4*c]=r.x; rb[4*c+1]=r.y; rb[4*c+2]=r.z; rb[4*c+3]=r.w;
    }
  }
  float A1[3], A2[3];
  {
    const float4* w1 = (const float4*)(ws + WS_WW + ((size_t)(Zj*2+0)*16+g)*48);
    const float4* w2 = (const float4*)(ws + WS_WW + ((size_t)(Zj*2+1)*16+g)*48);
    #pragma unroll
    for(int d=0; d<3; d++){
      float a1 = 0.f, a2 = 0.f;
      #pragma unroll
      for(int c=0;c<4;c++){
        float4 x1 = w1[d*4+c], x2 = w2[d*4+c];
        a1 += x1.x*rb[4*c] + x1.y*rb[4*c+1] + x1.z*rb[4*c+2] + x1.w*rb[4*c+3];
        a2 += x2.x*rb[4*c] + x2.y*rb[4*c+1] + x2.z*rb[4*c+2] + x2.w*rb[4*c+3];
      }
      A1[d] = a1; A2[d] = a2;
    }
  }
  __syncthreads();
  if(g < 9){
    const float* tdw = ws + WS_TDW;
    const int* tdij  = (const int*)ws + WS_TDIJ;
    const int* tdofs = (const int*)ws + WS_TDOFS;
    int e1 = tdofs[g+1];
    for(int e=tdofs[g]; e<e1; e++){
      float w = tdw[e]; int meta = tdij[e];
      int i = meta & 31, j = (meta>>5) & 15, li = (meta>>10) & 3, lj = (meta>>12) & 3;
      S_s[pl][g*9 + li*3 + lj] += w * sh_s[pl][i] * sh_s[pl][j];
    }
  }
  __syncthreads();
  float AA[9];
  #pragma unroll
  for(int li=0;li<3;li++)
    #pragma unroll
    for(int lj=0;lj<3;lj++) AA[li*3+lj] = A1[li]*A2[lj];
  #pragma unroll
  for(int k=0;k<9;k++){
    float tpv = 0.f;
    #pragma unroll
    for(int c=0;c<9;c++) tpv += S_s[pl][k*9+c] * AA[c];
    tp_s[pl][k][g] = tpv;
  }
  __syncthreads();
  float w3r[48];
  #pragma unroll
  for(int d=0;d<3;d++)
    #pragma unroll
    for(int f2=0;f2<16;f2++) w3r[d*16+f2] = W3[(d*16+f2)*16+g];
  float acc9[9];
  #pragma unroll
  for(int k=0;k<9;k++){
    int d = (k==0)?0:(k<4)?1:2;
    const float4* t4 = (const float4*)&tp_s[pl][k][0];
    float acc = 0.f;
    #pragma unroll
    for(int c=0;c<4;c++){
      float4 t = t4[c];
      acc += t.x*w3r[d*16+4*c] + t.y*w3r[d*16+4*c+1] + t.z*w3r[d*16+4*c+2] + t.w*w3r[d*16+4*c+3];
    }
    acc9[k] = scrub(acc);
  }
  // wide aligned stores: [sp][g][16] halves (full-line coverage per wave)
  f16* ptd = (f16*)(ws + WS_PVF) + (size_t)sp*256 + g*16;
  U4H u0, u1;
  #pragma unroll
  for(int j=0;j<8;j++) u0.h[j] = (f16)acc9[j];
  u1.h[0] = (f16)acc9[8];
  #pragma unroll
  for(int j=1;j<8;j++) u1.h[j] = (f16)0.f;
  *(uint4*)(ptd)     = u0.u;
  *(uint4*)(ptd + 8) = u1.u;
}

// ---------------- fused TD gather + layer-1 QKV (NL=3) ----------------
__global__ __launch_bounds__(256) void k_tdq(const float* Wq, const float* Wk,
                                             const float* Wv, float* ws){
  __shared__ float xsh[4][144];
  __shared__ float wq_sh[768], wk_sh[768], wv_sh[768];
  int tid = threadIdx.x, al = tid >> 6, lane = tid & 63;
  int a = blockIdx.x*4 + al;
  for(int t=tid; t<768; t+=256){ wq_sh[t]=Wq[t]; wk_sh[t]=Wk[t]; wv_sh[t]=Wv[t]; }
  const int* coff = (const int*)ws + WS_COFF;
  int off0 = coff[a], n = coff[a+1] - off0;
  const f16* base = (const f16*)(ws + WS_PVF);
  float acc[8] = {0,0,0,0,0,0,0,0};
  if(lane < 32){
    for(int t=0; t<n; t++){
      U4H u; u.u = *(const uint4*)(base + (size_t)(off0+t)*256 + lane*8);
      #pragma unroll
      for(int j=0;j<8;j++) acc[j] += (float)u.h[j];
    }
  }
  float invn = 1.f / fmaxf((float)n, 1.f);
  if(lane < 32){
    int gg = lane >> 1;
    #pragma unroll
    for(int j=0;j<8;j++){
      int k = (lane & 1)*8 + j;
      if(k < 9) xsh[al][k*16 + gg] = scrub(acc[j]*invn);
    }
  }
  __syncthreads();
  int g = lane & 15, q4 = lane >> 4;
  f16* qt = (f16*)(ws + WS_XQ) + (size_t)a*800 + g*32;
  f16* kt = (f16*)(ws + WS_XK) + (size_t)a*800 + g*32;
  f16* vt = (f16*)(ws + WS_XV) + (size_t)a*800 + g*32;
  for(int i=q4; i<9; i+=4){
    int l = (i==0)?0:(i<4)?1:2;
    float q=0.f, k2=0.f, v2=0.f;
    #pragma unroll
    for(int f2=0;f2<16;f2++){
      float xv = xsh[al][i*16+f2];
      q  += xv*wq_sh[(l*16+f2)*16+g];
      k2 += xv*wk_sh[(l*16+f2)*16+g];
      v2 += xv*wv_sh[(l*16+f2)*16+g];
    }
    qt[i] = (f16)q; kt[i] = (f16)k2; vt[i] = (f16)v2;
  }
}

// ---------------- merged attention, f16 M in LDS, wide pvf stores ----------
template<int NI>
__global__ __launch_bounds__(128) void k_att(const int* nbr, const float* Wb, float* ws){
  __shared__ __align__(16) f16 Ml[8][840];
  __shared__ float sh_s[8][9];
  constexpr int NPAIR = NI/2;
  constexpr int TAIL  = NI-1;
  int tid = threadIdx.x, pl = tid >> 4, g = tid & 15;
  int sp = blockIdx.x*8 + pl;
  int p = ((const int*)ws)[WS_CLST + sp];
  {
    uint4 z; z.x=0; z.y=0; z.z=0; z.w=0;
    uint4* Mz = (uint4*)&Ml[0][0];
    for(int t0=tid; t0<840; t0+=128) Mz[t0] = z;
  }
  if(g < 9) sh_s[pl][g] = ws[WS_SH + p*9 + g];
  // wbf via float4 rb + Wb row
  float wbf;
  {
    const float4* rb4 = (const float4*)(ws + WS_RB + p*16);
    float acc = 0.f;
    #pragma unroll
    for(int c=0;c<4;c++){
      float4 r = rb4[c];
      acc += r.x*Wb[(4*c)*16+g] + r.y*Wb[(4*c+1)*16+g] + r.z*Wb[(4*c+2)*16+g] + r.w*Wb[(4*c+3)*16+g];
    }
    wbf = acc;
  }
  __syncthreads();
  {
    const float* attw = ws + WS_ATTW;
    const int* attij  = (const int*)ws + WS_ATTIJ;
    const int* aofs   = (const int*)ws + WS_AOFS;
    for(int kr=g; kr<25; kr+=16){
      f16* Mrow = &Ml[pl][kr*32];
      int e = aofs[kr], e1 = aofs[kr+1];
      int meta = attij[e];
      int curi = meta & 31;
      float cur = 0.f;
      for(; e<e1; e++){
        meta = attij[e];
        int i2 = meta & 31;
        if(i2 != curi){ Mrow[curi] = (f16)cur; cur = 0.f; curi = i2; }
        cur += attw[e] * sh_s[pl][(meta>>5) & 15];
      }
      Mrow[curi] = (f16)cur;
    }
  }
  __syncthreads();
  int dst = nbr[2*p], src = nbr[2*p+1];
  float q_r[NI];
  {
    const f16* qt = (const f16*)(ws + WS_XQ) + (size_t)dst*800 + g*32;
    #pragma unroll
    for(int c=0;c<NPAIR/4;c++){
      U4H u; u.u = *(const uint4*)(qt + c*8);
      #pragma unroll
      for(int j=0;j<8;j++) q_r[c*8+j] = (float)u.h[j];
    }
    q_r[TAIL] = (float)qt[TAIL];
  }
  h2 xk2[NPAIR], xv2[NPAIR];
  float xkT, xvT;
  {
    const f16* kt = (const f16*)(ws + WS_XK) + (size_t)src*800 + g*32;
    const f16* vt = (const f16*)(ws + WS_XV) + (size_t)src*800 + g*32;
    #pragma unroll
    for(int c=0;c<NPAIR/4;c++){
      U4H uk; uk.u = *(const uint4*)(kt + c*8);
      U4H uv; uv.u = *(const uint4*)(vt + c*8);
      #pragma unroll
      for(int j=0;j<4;j++){ xk2[c*4+j] = uk.p[j]; xv2[c*4+j] = uv.p[j]; }
    }
    xkT = (float)kt[TAIL];
    xvT = (float)vt[TAIL];
  }
  float vvs[25];
  float sacc = 0.f;
  #pragma unroll
  for(int k=0;k<25;k++){
    const uint4* Mq = (const uint4*)&Ml[pl][k*32];
    float mT = (float)Ml[pl][k*32 + TAIL];
    float vv = 0.f, kf = 0.f;
    #pragma unroll
    for(int c=0;c<NPAIR/4;c++){
      U4H u; u.u = Mq[c];
      #pragma unroll
      for(int j=0;j<4;j++){
        vv = fdot2(u.p[j], xv2[c*4+j], vv);
        if(k < NI) kf = fdot2(u.p[j], xk2[c*4+j], kf);
      }
    }
    vv += mT * xvT;
    if(k < NI){
      kf += mT * xkT;
      sacc += q_r[k]*kf;
    }
    vvs[k] = wbf*vv;
  }
  // wide aligned stores: [sp][g][32] halves — wave covers contiguous 4KB
  f16* pvf = (f16*)(ws + WS_PVF) + (size_t)sp*512 + g*32;
  #pragma unroll
  for(int c=0;c<3;c++){
    U4H u;
    #pragma unroll
    for(int j=0;j<8;j++) u.h[j] = (f16)scrub(vvs[c*8+j]);
    *(uint4*)(pvf + c*8) = u.u;
  }
  {
    U4H u;
    u.h[0] = (f16)scrub(vvs[24]);
    #pragma unroll
    for(int j=1;j<8;j++) u.h[j] = (f16)0.f;
    *(uint4*)(pvf + 24) = u.u;
  }
  float sl = sacc;
  #pragma unroll
  for(int off=1; off<16; off<<=1) sl += __shfl_xor(sl, off, 16);
  if(g == 0) ws[WS_S + sp] = scrub(sl * 0.05f);   // / sqrt(25*16)
}

// ---------------- fused softmax-gather + output pdense (+QKV next / final) -
template<bool FINAL>
__global__ __launch_bounds__(256) void k_aggo(const float* Wo, const float* bo,
    const int* aZ, const float* emb, const float* Wemb, const float* bemb,
    const float* Wq, const float* Wk, const float* Wv, float* ws, float* out){
  __shared__ float xsh[4][400];
  __shared__ float wo_sh[1280];
  __shared__ float wq_sh[FINAL?4:1280], wk_sh[FINAL?4:1280], wv_sh[FINAL?4:1280];
  __shared__ float osh[FINAL?4:1600];
  int tid = threadIdx.x, al = tid >> 6, lane = tid & 63;
  int a = blockIdx.x*4 + al;
  for(int t=tid; t<1280; t+=256){
    wo_sh[t] = Wo[t];
    if(!FINAL){ wq_sh[t]=Wq[t]; wk_sh[t]=Wk[t]; wv_sh[t]=Wv[t]; }
  }
  const int* coff = (const int*)ws + WS_COFF;
  int off0 = coff[a], n = coff[a+1] - off0;
  // softmax stats: this atom == this wave
  float mx = -1e30f;
  for(int t=lane; t<n; t+=64) mx = fmaxf(mx, ws[WS_S + off0 + t]);
  #pragma unroll
  for(int off=1; off<64; off<<=1) mx = fmaxf(mx, __shfl_xor(mx, off));
  float den = 0.f;
  for(int t=lane; t<n; t+=64) den += expf(fminf(ws[WS_S + off0 + t] - mx, 0.f));
  #pragma unroll
  for(int off=1; off<64; off<<=1) den += __shfl_xor(den, off);
  float inv_den = 1.f / (den + 1e-9f);
  // alpha-weighted gather of pvf [sp][g][32]
  float acc[8] = {0,0,0,0,0,0,0,0};
  const f16* base = (const f16*)(ws + WS_PVF);
  for(int t=0; t<n; t++){
    float alpha = expf(fminf(ws[WS_S + off0 + t] - mx, 0.f)) * inv_den;
    U4H u; u.u = *(const uint4*)(base + (size_t)(off0+t)*512 + lane*8);
    #pragma unroll
    for(int j=0;j<8;j++) acc[j] += alpha * (float)u.h[j];
  }
  {
    int g4 = lane >> 2, sl0 = (lane & 3)*8;
    #pragma unroll
    for(int j=0;j<8;j++){
      int slot = sl0 + j;
      if(slot < 25) xsh[al][slot*16 + g4] = scrub(acc[j]);
    }
  }
  __syncthreads();
  int g = lane & 15, q4 = lane >> 4;
  // output pdense
  for(int i=q4; i<25; i+=4){
    int l = (i==0)?0:(i<4)?1:(i<9)?2:(i<16)?3:4;
    float accv = 0.f;
    #pragma unroll
    for(int f2=0;f2<16;f2++) accv += xsh[al][i*16+f2]*wo_sh[(l*16+f2)*16+g];
    if(i == 0){
      accv += bo[g];
      if(FINAL){
        int Z = aZ[a];
        float res = bemb[g];
        #pragma unroll
        for(int e2=0;e2<32;e2++) res += emb[Z*32+e2]*Wemb[e2*16+g];
        accv += res;
      }
    }
    if(FINAL) out[a*400 + i*16 + g] = scrub(accv);
    else      osh[al*400 + i*16 + g] = scrub(accv);
  }
  if(!FINAL){
    __syncthreads();
    f16* qt = (f16*)(ws + WS_XQ) + (size_t)a*800 + g*32;
    f16* kt = (f16*)(ws + WS_XK) + (size_t)a*800 + g*32;
    f16* vt = (f16*)(ws + WS_XV) + (size_t)a*800 + g*32;
    for(int i=q4; i<25; i+=4){
      int l = (i==0)?0:(i<4)?1:(i<9)?2:(i<16)?3:4;
      float q=0.f, k2=0.f, v2=0.f;
      #pragma unroll
      for(int f2=0;f2<16;f2++){
        float xv = osh[al*400 + i*16 + f2];
        q  += xv*wq_sh[(l*16+f2)*16+g];
        k2 += xv*wk_sh[(l*16+f2)*16+g];
        v2 += xv*wv_sh[(l*16+f2)*16+g];
      }
      qt[i] = (f16)q; kt[i] = (f16)k2; vt[i] = (f16)v2;
    }
  }
}

extern "C" void kernel_launch(void* const* d_in, const int* in_sizes, int n_in,
                              void* d_out, int out_size, void* d_ws, size_t ws_size,
                              hipStream_t stream){
  (void)in_sizes; (void)n_in; (void)out_size;
  if(ws_size < (size_t)WS_END * sizeof(float)) return;
  float* ws = (float*)d_ws;
  const int* aZ  = (const int*)d_in[0];
  const int* nbr = (const int*)d_in[1];
  const float* disp = (const float*)d_in[2];
  const float* Wrad = (const float*)d_in[3];
  const float* emb  = (const float*)d_in[4];
  const float* Wemb = (const float*)d_in[5];
  const float* bemb = (const float*)d_in[6];
  const float* W1   = (const float*)d_in[7];
  const float* W2   = (const float*)d_in[8];
  const float* W3   = (const float*)d_in[9];
  const float* Wb1 = (const float*)d_in[10]; const float* Wq1 = (const float*)d_in[11];
  const float* Wk1 = (const float*)d_in[12]; const float* Wv1 = (const float*)d_in[13];
  const float* Wo1 = (const float*)d_in[14]; const float* bo1 = (const float*)d_in[15];
  const float* Wb2 = (const float*)d_in[16]; const float* Wq2 = (const float*)d_in[17];
  const float* Wk2 = (const float*)d_in[18]; const float* Wv2 = (const float*)d_in[19];
  const float* Wo2 = (const float*)d_in[20]; const float* bo2 = (const float*)d_in[21];

  kq_G<<<22,256,0,stream>>>(ws);
  kq_lists<<<1,64,0,stream>>>(ws);
  k_pair<<<192,256,0,stream>>>(disp, ws);
  hipMemsetAsync(ws + WS_CCNT, 0, NA*sizeof(int), stream);
  k_cnt<<<192,256,0,stream>>>(nbr, ws);
  k_scan<<<1,1024,0,stream>>>(ws);
  k_fill<<<192,256,0,stream>>>(nbr, ws);
  k_ww<<<95,256,0,stream>>>(Wrad, W1, W2, ws);
  k_td<<<3072,256,0,stream>>>(aZ, nbr, W3, ws);
  k_tdq<<<1024,256,0,stream>>>(Wq1, Wk1, Wv1, ws);

  k_att<9><<<6144,128,0,stream>>>(nbr, Wb1, ws);
  k_aggo<false><<<1024,256,0,stream>>>(Wo1, bo1, aZ, emb, Wemb, bemb,
                                       Wq2, Wk2, Wv2, ws, nullptr);
  k_att<25><<<6144,128,0,stream>>>(nbr, Wb2, ws);
  k_aggo<true><<<1024,256,0,stream>>>(Wo2, bo2, aZ, emb, Wemb, bemb,
                                      nullptr, nullptr, nullptr, ws, (float*)d_out);
}

// Round 10
// 474.060 us; speedup vs baseline: 1.0337x; 1.0205x over previous
//
#include <hip/hip_runtime.h>
#include <hip/hip_bf16.h>

#define NA 4096
#define NP 49152

typedef _Float16 f16;
typedef _Float16 h2 __attribute__((ext_vector_type(2)));
union U4H { uint4 u; f16 h[8]; h2 p[4]; };

__device__ __forceinline__ float fdot2(h2 a, h2 b, float c){
#if __has_builtin(__builtin_amdgcn_fdot2)
  return __builtin_amdgcn_fdot2(a, b, c, false);
#else
  return c + (float)a.x*(float)b.x + (float)a.y*(float)b.y;
#endif
}

// ---------------- ws layout (float-element offsets) ----------------
constexpr int WS_Y     = 0;                    // (unused, kept for layout)
constexpr int WS_G     = 12800;                // 5625 Gaunt tensor
constexpr int WS_NATT  = WS_G + 5632;          // int
constexpr int WS_ATTW  = WS_NATT + 8;          // 1024 floats
constexpr int WS_ATTIJ = WS_ATTW + 1024;       // 1024 ints, sorted by k (i-major inside)
constexpr int WS_TDOFS = WS_ATTIJ + 1024;      // 16 ints
constexpr int WS_TDW   = WS_TDOFS + 16;        // 512 floats
constexpr int WS_TDIJ  = WS_TDW + 512;         // 512 ints
constexpr int WS_AOFS  = WS_TDIJ + 512;        // 32 ints
constexpr int WS_SH    = WS_AOFS + 32;         // NP*9
constexpr int WS_RB    = WS_SH + NP*9;         // NP*16
constexpr int WS_S     = WS_RB + NP*16;        // NP scores (sorted index)
constexpr int WS_CCNT  = WS_S + NP;            // NA ints
constexpr int WS_COFF  = WS_CCNT + NA;         // NA+1 ints
constexpr int WS_CCUR  = WS_COFF + NA + 8;     // NA ints
constexpr int WS_CLST  = WS_CCUR + NA;         // NP ints (pair ids sorted by dst)
constexpr int WS_XQ    = WS_CLST + NP;         // f16 transposed q (NA*800 halves)
constexpr int WS_XK    = WS_XQ + NA*400;
constexpr int WS_XV    = WS_XK + NA*400;
constexpr int WS_PVF   = WS_XV + NA*400;       // f16 stream: att [sp][g][32] / td [sp][g][16]
constexpr int WS_WW    = WS_PVF + NP*128;      // 145920 floats (dead after k_td)
constexpr long long WS_END = (long long)WS_PVF + (long long)NP*256;  // ~76 MB

__device__ const float  GLX[16] = {
  -0.98940093499164993f, -0.94457502307323258f, -0.86563120238783174f, -0.75540440835500303f,
  -0.61787624440264375f, -0.45801677765722739f, -0.28160355077925891f, -0.09501250983763744f,
   0.09501250983763744f,  0.28160355077925891f,  0.45801677765722739f,  0.61787624440264375f,
   0.75540440835500303f,  0.86563120238783174f,  0.94457502307323258f,  0.98940093499164993f };
__device__ const double GLW[16] = {
  0.02715245941175409, 0.06225352393864789, 0.09515851168249278, 0.12462897125553387,
  0.14959598881657673, 0.16915651939500254, 0.18260341504492359, 0.18945061045506850,
  0.18945061045506850, 0.18260341504492359, 0.16915651939500254, 0.14959598881657673,
  0.12462897125553387, 0.09515851168249278, 0.06225352393864789, 0.02715245941175409 };

#define PI_D 3.14159265358979323846

__device__ __forceinline__ float scrub(float v){
  if(!(v == v)) return 0.f;
  return fminf(fmaxf(v, -1e30f), 1e30f);
}

__device__ void real_sph25(float ct, float phi, float* Y){
  float st = sqrtf(fmaxf(0.f, 1.f - ct*ct));
  float P[5][5];
  P[0][0] = 1.f;
  #pragma unroll
  for(int m=1;m<=4;m++) P[m][m] = -(2.f*m - 1.f)*st*P[m-1][m-1];
  #pragma unroll
  for(int m=0;m<4;m++) P[m+1][m] = (2.f*m + 1.f)*ct*P[m][m];
  #pragma unroll
  for(int m=0;m<=4;m++){
    #pragma unroll
    for(int l=m+2;l<=4;l++)
      P[l][m] = ((2.f*l - 1.f)*ct*P[l-1][m] - (float)(l+m-1)*P[l-2][m]) / (float)(l-m);
  }
  const double fact[9] = {1,1,2,6,24,120,720,5040,40320};
  int idx = 0;
  #pragma unroll
  for(int l=0;l<=4;l++){
    #pragma unroll
    for(int m=-l;m<=l;m++){
      int ma = (m < 0) ? -m : m;
      float Nn = (float)sqrt((2*l+1)/(4.0*PI_D)*fact[l-ma]/fact[l+ma]);
      float cs = (ma & 1) ? -1.f : 1.f;
      float v;
      if(m == 0)      v = Nn * P[l][0];
      else if(m > 0)  v = 1.4142135623730951f * Nn * cs * cosf(ma*phi) * P[l][ma];
      else            v = 1.4142135623730951f * Nn * cs * sinf(ma*phi) * P[l][ma];
      Y[idx++] = v;
    }
  }
}

// G kernel: Y recomputed per block; quadrature split 8-way per (i,j,k)
// (breaks the 512-long serial f64 chain into 64 + wave reduce)
__global__ __launch_bounds__(256) void kq_G(float* ws){
  __shared__ float Ysh[12800];
  int tid = threadIdx.x;
  for(int pt=tid; pt<512; pt+=256){
    float ct  = GLX[pt >> 5];
    float phi = (float)((pt & 31) * (2.0*PI_D/32.0));
    float Y[25];
    real_sph25(ct, phi, Y);
    #pragma unroll
    for(int i=0;i<25;i++) Ysh[pt*25 + i] = Y[i];
  }
  __syncthreads();
  int idx = blockIdx.x*256 + tid;
  int t = idx >> 3, chunk = idx & 7;
  if(t >= 5625) return;
  int k = t % 25, j = (t/25) % 9, i = t/225;
  double acc = 0.0;
  int g0 = chunk*64;
  #pragma unroll 4
  for(int g=g0; g<g0+64; g++){
    double w = GLW[g >> 5] * (2.0*PI_D/32.0);
    acc += w * (double)Ysh[g*25+i] * (double)Ysh[g*25+j] * (double)Ysh[g*25+k];
  }
  acc += __shfl_xor(acc, 1, 8);
  acc += __shfl_xor(acc, 2, 8);
  acc += __shfl_xor(acc, 4, 8);
  if(chunk == 0){
    if(fabs(acc) < 1e-6) acc = 0.0;
    ws[WS_G + (i*9+j)*25 + k] = (float)acc;
  }
}

__global__ void kq_lists(float* ws){
  __shared__ int cA[25], cT[9], oA[26], oT[10];
  int t = threadIdx.x;
  const float* G = ws + WS_G;
  if(t < 25){ int c=0; for(int i=0;i<25;i++) for(int j=0;j<9;j++) if(G[(i*9+j)*25+t] != 0.f) c++; cA[t]=c; }
  if(t < 9){  int c=0; for(int i=0;i<9;i++)  for(int j=0;j<9;j++) if(G[(i*9+j)*25+t] != 0.f) c++; cT[t]=c; }
  __syncthreads();
  if(t == 0){
    int s=0; for(int k=0;k<25;k++){ oA[k]=s; s+=cA[k]; } oA[25]=s;
    ((int*)ws)[WS_NATT] = s;
    s=0; for(int k=0;k<9;k++){ oT[k]=s; s+=cT[k]; } oT[9]=s;
  }
  __syncthreads();
  float* attw = ws + WS_ATTW; int* attij = (int*)ws + WS_ATTIJ;
  int* aofs = (int*)ws + WS_AOFS;
  if(t < 26) aofs[t] = oA[t] < 1024 ? oA[t] : 1024;
  if(t < 25){
    int pos = oA[t];
    for(int i=0;i<25;i++) for(int j=0;j<9;j++){
      float w = G[(i*9+j)*25+t];
      if(w != 0.f && pos < 1024){ attw[pos]=w; attij[pos] = i | (j<<5) | (t<<9); pos++; }
    }
  }
  float* tdw = ws + WS_TDW; int* tdij = (int*)ws + WS_TDIJ; int* tdofs = (int*)ws + WS_TDOFS;
  if(t < 9){
    int pos = oT[t];
    for(int i=0;i<9;i++) for(int j=0;j<9;j++){
      float w = G[(i*9+j)*25+t];
      if(w != 0.f && pos < 512){
        int li = (i==0)?0:(i<4)?1:2, lj = (j==0)?0:(j<4)?1:2;
        tdw[pos]=w; tdij[pos] = i | (j<<5) | (li<<10) | (lj<<12); pos++;
      }
    }
    tdofs[t] = oT[t];
    if(t == 0) tdofs[9] = oT[9];
  }
}

__global__ void k_pair(const float* disp, float* ws){
  int p = blockIdx.x*256 + threadIdx.x;
  if(p >= NP) return;
  float dx = disp[3*p], dy = disp[3*p+1], dz = disp[3*p+2];
  float r = sqrtf(dx*dx + dy*dy + dz*dz);
  float inv = 1.f / fmaxf(r, 1e-9f);
  float ux = dx*inv, uy = dy*inv, uz = dz*inv;
  float sh[9];
  sh[0] = 0.28209479177387814f;
  sh[1] = 0.4886025119029199f * uy;
  sh[2] = 0.4886025119029199f * uz;
  sh[3] = 0.4886025119029199f * ux;
  sh[4] = 1.0925484305920792f * ux*uy;
  sh[5] = 1.0925484305920792f * uy*uz;
  sh[6] = 0.31539156525252005f * (3.f*uz*uz - 1.f);
  sh[7] = 1.0925484305920792f * ux*uz;
  sh[8] = 0.5462742152960396f * (ux*ux - uy*uy);
  #pragma unroll
  for(int i=0;i<9;i++) ws[WS_SH + p*9 + i] = scrub(sh[i]);
  float mask = (r < 5.f) ? 1.f : 0.f;
  #pragma unroll
  for(int k=1;k<=16;k++){
    float x  = (float)k * r * 0.2f;
    float px = 3.14159265358979323846f * x;
    float s  = (px < 1e-6f) ? 1.f : (sinf(px)/px);
    ws[WS_RB + p*16 + (k-1)] = scrub(s * mask);
  }
}

// ---------------- CSR by dst ----------------
__global__ void k_cnt(const int* nbr, float* ws){
  int p = blockIdx.x*256 + threadIdx.x;
  if(p >= NP) return;
  atomicAdd((int*)ws + WS_CCNT + nbr[2*p], 1);
}

__global__ __launch_bounds__(1024) void k_scan(float* ws){
  __shared__ int part[1024];
  int t = threadIdx.x;
  const int* cnt = (const int*)ws + WS_CCNT;
  int v0 = cnt[4*t], v1 = cnt[4*t+1], v2 = cnt[4*t+2], v3 = cnt[4*t+3];
  part[t] = v0+v1+v2+v3;
  __syncthreads();
  for(int o=1; o<1024; o<<=1){
    int x = (t >= o) ? part[t-o] : 0;
    __syncthreads();
    part[t] += x;
    __syncthreads();
  }
  int base = (t > 0) ? part[t-1] : 0;
  int* offp = (int*)ws + WS_COFF;
  int* cur  = (int*)ws + WS_CCUR;
  offp[4*t]   = base;          cur[4*t]   = base;
  offp[4*t+1] = base+v0;       cur[4*t+1] = base+v0;
  offp[4*t+2] = base+v0+v1;    cur[4*t+2] = base+v0+v1;
  offp[4*t+3] = base+v0+v1+v2; cur[4*t+3] = base+v0+v1+v2;
  if(t == 1023) offp[4096] = part[1023];
}

__global__ void k_fill(const int* nbr, float* ws){
  int p = blockIdx.x*256 + threadIdx.x;
  if(p >= NP) return;
  int d = nbr[2*p];
  int pos = atomicAdd((int*)ws + WS_CCUR + d, 1);
  ((int*)ws)[WS_CLST + pos] = p;
}

// ---------------- WW prefold: WW[s][w][g][d][k] ----------------
__global__ __launch_bounds__(256) void k_ww(const float* Wrad, const float* W1,
                                            const float* W2, float* ws){
  int s = blockIdx.x;
  #pragma unroll
  for(int it=0; it<6; it++){
    int idx = threadIdx.x + 256*it;
    int w = idx / 768, r = idx % 768;
    int d = r / 256, r2 = r % 256, k = r2 / 16, g = r2 % 16;
    const float* Wsrc = (w == 0) ? W1 : W2;
    float acc = 0.f;
    #pragma unroll
    for(int fp=0; fp<16; fp++)
      acc += Wrad[(s*16+k)*16+fp] * Wsrc[(d*16+fp)*16+g];
    ws[WS_WW + ((size_t)(s*2+w)*16 + g)*48 + d*16 + k] = acc;
  }
}

// ---------------- TD phase: WW-folded A, S-matrix Gaunt, wide f16 stores ---
__global__ __launch_bounds__(256) void k_td(const int* aZ, const int* nbr,
    const float* W3, float* ws){
  __shared__ float sh_s[16][9];
  __shared__ float S_s[16][88];
  __shared__ float tp_s[16][9][16];
  int tid = threadIdx.x, pl = tid >> 4, g = tid & 15;
  int sp = blockIdx.x*16 + pl;
  int p = ((const int*)ws)[WS_CLST + sp];
  int src = nbr[2*p+1];
  int Zj = aZ[src];
  {
    float4* S4 = (float4*)&S_s[0][0];
    for(int t0=tid; t0<352; t0+=256) S4[t0] = make_float4(0.f,0.f,0.f,0.f);
  }
  if(g < 9) sh_s[pl][g] = ws[WS_SH + p*9 + g];
  float rb[16];
  {
    const float4* rb4 = (const float4*)(ws + WS_RB + p*16);
    #pragma unroll
    for(int c=0;c<4;c++){
      float4 r = rb4[c];
      rb[4*c]=r.x; rb[4*c+1]=r.y; rb[4*c+2]=r.z; rb[4*c+3]=r.w;
    }
  }
  float A1[3], A2[3];
  {
    const float4* w1 = (const float4*)(ws + WS_WW + ((size_t)(Zj*2+0)*16+g)*48);
    const float4* w2 = (const float4*)(ws + WS_WW + ((size_t)(Zj*2+1)*16+g)*48);
    #pragma unroll
    for(int d=0; d<3; d++){
      float a1 = 0.f, a2 = 0.f;
      #pragma unroll
      for(int c=0;c<4;c++){
        float4 x1 = w1[d*4+c], x2 = w2[d*4+c];
        a1 += x1.x*rb[4*c] + x1.y*rb[4*c+1] + x1.z*rb[4*c+2] + x1.w*rb[4*c+3];
        a2 += x2.x*rb[4*c] + x2.y*rb[4*c+1] + x2.z*rb[4*c+2] + x2.w*rb[4*c+3];
      }
      A1[d] = a1; A2[d] = a2;
    }
  }
  __syncthreads();
  if(g < 9){
    const float* tdw = ws + WS_TDW;
    const int* tdij  = (const int*)ws + WS_TDIJ;
    const int* tdofs = (const int*)ws + WS_TDOFS;
    int e1 = tdofs[g+1];
    for(int e=tdofs[g]; e<e1; e++){
      float w = tdw[e]; int meta = tdij[e];
      int i = meta & 31, j = (meta>>5) & 15, li = (meta>>10) & 3, lj = (meta>>12) & 3;
      S_s[pl][g*9 + li*3 + lj] += w * sh_s[pl][i] * sh_s[pl][j];
    }
  }
  __syncthreads();
  float AA[9];
  #pragma unroll
  for(int li=0;li<3;li++)
    #pragma unroll
    for(int lj=0;lj<3;lj++) AA[li*3+lj] = A1[li]*A2[lj];
  #pragma unroll
  for(int k=0;k<9;k++){
    float tpv = 0.f;
    #pragma unroll
    for(int c=0;c<9;c++) tpv += S_s[pl][k*9+c] * AA[c];
    tp_s[pl][k][g] = tpv;
  }
  __syncthreads();
  float w3r[48];
  #pragma unroll
  for(int d=0;d<3;d++)
    #pragma unroll
    for(int f2=0;f2<16;f2++) w3r[d*16+f2] = W3[(d*16+f2)*16+g];
  float acc9[9];
  #pragma unroll
  for(int k=0;k<9;k++){
    int d = (k==0)?0:(k<4)?1:2;
    const float4* t4 = (const float4*)&tp_s[pl][k][0];
    float acc = 0.f;
    #pragma unroll
    for(int c=0;c<4;c++){
      float4 t = t4[c];
      acc += t.x*w3r[d*16+4*c] + t.y*w3r[d*16+4*c+1] + t.z*w3r[d*16+4*c+2] + t.w*w3r[d*16+4*c+3];
    }
    acc9[k] = scrub(acc);
  }
  f16* ptd = (f16*)(ws + WS_PVF) + (size_t)sp*256 + g*16;
  U4H u0, u1;
  #pragma unroll
  for(int j=0;j<8;j++) u0.h[j] = (f16)acc9[j];
  u1.h[0] = (f16)acc9[8];
  #pragma unroll
  for(int j=1;j<8;j++) u1.h[j] = (f16)0.f;
  *(uint4*)(ptd)     = u0.u;
  *(uint4*)(ptd + 8) = u1.u;
}

// ---------------- fused TD gather + layer-1 QKV (NL=3) ----------------
__global__ __launch_bounds__(256) void k_tdq(const float* Wq, const float* Wk,
                                             const float* Wv, float* ws){
  __shared__ float xsh[4][144];
  __shared__ float wq_sh[768], wk_sh[768], wv_sh[768];
  int tid = threadIdx.x, al = tid >> 6, lane = tid & 63;
  int a = blockIdx.x*4 + al;
  for(int t=tid; t<768; t+=256){ wq_sh[t]=Wq[t]; wk_sh[t]=Wk[t]; wv_sh[t]=Wv[t]; }
  const int* coff = (const int*)ws + WS_COFF;
  int off0 = coff[a], n = coff[a+1] - off0;
  const f16* base = (const f16*)(ws + WS_PVF);
  float acc[8] = {0,0,0,0,0,0,0,0};
  if(lane < 32){
    for(int t=0; t<n; t++){
      U4H u; u.u = *(const uint4*)(base + (size_t)(off0+t)*256 + lane*8);
      #pragma unroll
      for(int j=0;j<8;j++) acc[j] += (float)u.h[j];
    }
  }
  float invn = 1.f / fmaxf((float)n, 1.f);
  if(lane < 32){
    int gg = lane >> 1;
    #pragma unroll
    for(int j=0;j<8;j++){
      int k = (lane & 1)*8 + j;
      if(k < 9) xsh[al][k*16 + gg] = scrub(acc[j]*invn);
    }
  }
  __syncthreads();
  int g = lane & 15, q4 = lane >> 4;
  f16* qt = (f16*)(ws + WS_XQ) + (size_t)a*800 + g*32;
  f16* kt = (f16*)(ws + WS_XK) + (size_t)a*800 + g*32;
  f16* vt = (f16*)(ws + WS_XV) + (size_t)a*800 + g*32;
  for(int i=q4; i<9; i+=4){
    int l = (i==0)?0:(i<4)?1:2;
    float q=0.f, k2=0.f, v2=0.f;
    #pragma unroll
    for(int f2=0;f2<16;f2++){
      float xv = xsh[al][i*16+f2];
      q  += xv*wq_sh[(l*16+f2)*16+g];
      k2 += xv*wk_sh[(l*16+f2)*16+g];
      v2 += xv*wv_sh[(l*16+f2)*16+g];
    }
    qt[i] = (f16)q; kt[i] = (f16)k2; vt[i] = (f16)v2;
  }
}

// ---------------- merged attention: loads hoisted before M-build barriers --
template<int NI>
__global__ __launch_bounds__(128) void k_att(const int* nbr, const float* Wb, float* ws){
  __shared__ __align__(16) f16 Ml[8][840];
  __shared__ float sh_s[8][9];
  constexpr int NPAIR = NI/2;
  constexpr int TAIL  = NI-1;
  int tid = threadIdx.x, pl = tid >> 4, g = tid & 15;
  int sp = blockIdx.x*8 + pl;
  int p = ((const int*)ws)[WS_CLST + sp];
  {
    uint4 z; z.x=0; z.y=0; z.z=0; z.w=0;
    uint4* Mz = (uint4*)&Ml[0][0];
    for(int t0=tid; t0<840; t0+=128) Mz[t0] = z;
  }
  if(g < 9) sh_s[pl][g] = ws[WS_SH + p*9 + g];
  // ---- EARLY global loads: issued before the barriers so the M build
  // hides their latency (barrier drains vmcnt while LDS work proceeds) ----
  int dst = nbr[2*p], src = nbr[2*p+1];
  float q_r[NI];
  {
    const f16* qt = (const f16*)(ws + WS_XQ) + (size_t)dst*800 + g*32;
    #pragma unroll
    for(int c=0;c<NPAIR/4;c++){
      U4H u; u.u = *(const uint4*)(qt + c*8);
      #pragma unroll
      for(int j=0;j<8;j++) q_r[c*8+j] = (float)u.h[j];
    }
    q_r[TAIL] = (float)qt[TAIL];
  }
  h2 xk2[NPAIR], xv2[NPAIR];
  float xkT, xvT;
  {
    const f16* kt = (const f16*)(ws + WS_XK) + (size_t)src*800 + g*32;
    const f16* vt = (const f16*)(ws + WS_XV) + (size_t)src*800 + g*32;
    #pragma unroll
    for(int c=0;c<NPAIR/4;c++){
      U4H uk; uk.u = *(const uint4*)(kt + c*8);
      U4H uv; uv.u = *(const uint4*)(vt + c*8);
      #pragma unroll
      for(int j=0;j<4;j++){ xk2[c*4+j] = uk.p[j]; xv2[c*4+j] = uv.p[j]; }
    }
    xkT = (float)kt[TAIL];
    xvT = (float)vt[TAIL];
  }
  float wbf;
  {
    const float4* rb4 = (const float4*)(ws + WS_RB + p*16);
    float acc = 0.f;
    #pragma unroll
    for(int c=0;c<4;c++){
      float4 r = rb4[c];
      acc += r.x*Wb[(4*c)*16+g] + r.y*Wb[(4*c+1)*16+g] + r.z*Wb[(4*c+2)*16+g] + r.w*Wb[(4*c+3)*16+g];
    }
    wbf = acc;
  }
  __syncthreads();
  {
    const float* attw = ws + WS_ATTW;
    const int* attij  = (const int*)ws + WS_ATTIJ;
    const int* aofs   = (const int*)ws + WS_AOFS;
    for(int kr=g; kr<25; kr+=16){
      f16* Mrow = &Ml[pl][kr*32];
      int e = aofs[kr], e1 = aofs[kr+1];
      int meta = attij[e];
      int curi = meta & 31;
      float cur = 0.f;
      for(; e<e1; e++){
        meta = attij[e];
        int i2 = meta & 31;
        if(i2 != curi){ Mrow[curi] = (f16)cur; cur = 0.f; curi = i2; }
        cur += attw[e] * sh_s[pl][(meta>>5) & 15];
      }
      Mrow[curi] = (f16)cur;
    }
  }
  __syncthreads();
  // sweep; pvf packed incrementally (8 live halves, not 25 f32)
  f16* pvf = (f16*)(ws + WS_PVF) + (size_t)sp*512 + g*32;
  float sacc = 0.f;
  U4H up;
  #pragma unroll
  for(int k=0;k<25;k++){
    const uint4* Mq = (const uint4*)&Ml[pl][k*32];
    float mT = (float)Ml[pl][k*32 + TAIL];
    float vv = 0.f, kf = 0.f;
    #pragma unroll
    for(int c=0;c<NPAIR/4;c++){
      U4H u; u.u = Mq[c];
      #pragma unroll
      for(int j=0;j<4;j++){
        vv = fdot2(u.p[j], xv2[c*4+j], vv);
        if(k < NI) kf = fdot2(u.p[j], xk2[c*4+j], kf);
      }
    }
    vv += mT * xvT;
    if(k < NI){
      kf += mT * xkT;
      sacc += q_r[k]*kf;
    }
    up.h[k & 7] = (f16)scrub(wbf*vv);
    if((k & 7) == 7) *(uint4*)(pvf + (k >> 3)*8) = up.u;
  }
  {
    #pragma unroll
    for(int j=1;j<8;j++) up.h[j] = (f16)0.f;
    *(uint4*)(pvf + 24) = up.u;
  }
  float sl = sacc;
  #pragma unroll
  for(int off=1; off<16; off<<=1) sl += __shfl_xor(sl, off, 16);
  if(g == 0) ws[WS_S + sp] = scrub(sl * 0.05f);   // / sqrt(25*16)
}

// ---------------- fused softmax-gather + output pdense (+QKV next / final) -
template<bool FINAL>
__global__ __launch_bounds__(256) void k_aggo(const float* Wo, const float* bo,
    const int* aZ, const float* emb, const float* Wemb, const float* bemb,
    const float* Wq, const float* Wk, const float* Wv, float* ws, float* out){
  __shared__ float xsh[4][400];
  __shared__ float wo_sh[1280];
  __shared__ float wq_sh[FINAL?4:1280], wk_sh[FINAL?4:1280], wv_sh[FINAL?4:1280];
  __shared__ float osh[FINAL?4:1600];
  int tid = threadIdx.x, al = tid >> 6, lane = tid & 63;
  int a = blockIdx.x*4 + al;
  for(int t=tid; t<1280; t+=256){
    wo_sh[t] = Wo[t];
    if(!FINAL){ wq_sh[t]=Wq[t]; wk_sh[t]=Wk[t]; wv_sh[t]=Wv[t]; }
  }
  const int* coff = (const int*)ws + WS_COFF;
  int off0 = coff[a], n = coff[a+1] - off0;
  float mx = -1e30f;
  for(int t=lane; t<n; t+=64) mx = fmaxf(mx, ws[WS_S + off0 + t]);
  #pragma unroll
  for(int off=1; off<64; off<<=1) mx = fmaxf(mx, __shfl_xor(mx, off));
  float den = 0.f;
  for(int t=lane; t<n; t+=64) den += expf(fminf(ws[WS_S + off0 + t] - mx, 0.f));
  #pragma unroll
  for(int off=1; off<64; off<<=1) den += __shfl_xor(den, off);
  float inv_den = 1.f / (den + 1e-9f);
  float acc[8] = {0,0,0,0,0,0,0,0};
  const f16* base = (const f16*)(ws + WS_PVF);
  for(int t=0; t<n; t++){
    float alpha = expf(fminf(ws[WS_S + off0 + t] - mx, 0.f)) * inv_den;
    U4H u; u.u = *(const uint4*)(base + (size_t)(off0+t)*512 + lane*8);
    #pragma unroll
    for(int j=0;j<8;j++) acc[j] += alpha * (float)u.h[j];
  }
  {
    int g4 = lane >> 2, sl0 = (lane & 3)*8;
    #pragma unroll
    for(int j=0;j<8;j++){
      int slot = sl0 + j;
      if(slot < 25) xsh[al][slot*16 + g4] = scrub(acc[j]);
    }
  }
  __syncthreads();
  int g = lane & 15, q4 = lane >> 4;
  for(int i=q4; i<25; i+=4){
    int l = (i==0)?0:(i<4)?1:(i<9)?2:(i<16)?3:4;
    float accv = 0.f;
    #pragma unroll
    for(int f2=0;f2<16;f2++) accv += xsh[al][i*16+f2]*wo_sh[(l*16+f2)*16+g];
    if(i == 0){
      accv += bo[g];
      if(FINAL){
        int Z = aZ[a];
        float res = bemb[g];
        #pragma unroll
        for(int e2=0;e2<32;e2++) res += emb[Z*32+e2]*Wemb[e2*16+g];
        accv += res;
      }
    }
    if(FINAL) out[a*400 + i*16 + g] = scrub(accv);
    else      osh[al*400 + i*16 + g] = scrub(accv);
  }
  if(!FINAL){
    __syncthreads();
    f16* qt = (f16*)(ws + WS_XQ) + (size_t)a*800 + g*32;
    f16* kt = (f16*)(ws + WS_XK) + (size_t)a*800 + g*32;
    f16* vt = (f16*)(ws + WS_XV) + (size_t)a*800 + g*32;
    for(int i=q4; i<25; i+=4){
      int l = (i==0)?0:(i<4)?1:(i<9)?2:(i<16)?3:4;
      float q=0.f, k2=0.f, v2=0.f;
      #pragma unroll
      for(int f2=0;f2<16;f2++){
        float xv = osh[al*400 + i*16 + f2];
        q  += xv*wq_sh[(l*16+f2)*16+g];
        k2 += xv*wk_sh[(l*16+f2)*16+g];
        v2 += xv*wv_sh[(l*16+f2)*16+g];
      }
      qt[i] = (f16)q; kt[i] = (f16)k2; vt[i] = (f16)v2;
    }
  }
}

extern "C" void kernel_launch(void* const* d_in, const int* in_sizes, int n_in,
                              void* d_out, int out_size, void* d_ws, size_t ws_size,
                              hipStream_t stream){
  (void)in_sizes; (void)n_in; (void)out_size;
  if(ws_size < (size_t)WS_END * sizeof(float)) return;
  float* ws = (float*)d_ws;
  const int* aZ  = (const int*)d_in[0];
  const int* nbr = (const int*)d_in[1];
  const float* disp = (const float*)d_in[2];
  const float* Wrad = (const float*)d_in[3];
  const float* emb  = (const float*)d_in[4];
  const float* Wemb = (const float*)d_in[5];
  const float* bemb = (const float*)d_in[6];
  const float* W1   = (const float*)d_in[7];
  const float* W2   = (const float*)d_in[8];
  const float* W3   = (const float*)d_in[9];
  const float* Wb1 = (const float*)d_in[10]; const float* Wq1 = (const float*)d_in[11];
  const float* Wk1 = (const float*)d_in[12]; const float* Wv1 = (const float*)d_in[13];
  const float* Wo1 = (const float*)d_in[14]; const float* bo1 = (const float*)d_in[15];
  const float* Wb2 = (const float*)d_in[16]; const float* Wq2 = (const float*)d_in[17];
  const float* Wk2 = (const float*)d_in[18]; const float* Wv2 = (const float*)d_in[19];
  const float* Wo2 = (const float*)d_in[20]; const float* bo2 = (const float*)d_in[21];

  kq_G<<<176,256,0,stream>>>(ws);
  kq_lists<<<1,64,0,stream>>>(ws);
  k_pair<<<192,256,0,stream>>>(disp, ws);
  hipMemsetAsync(ws + WS_CCNT, 0, NA*sizeof(int), stream);
  k_cnt<<<192,256,0,stream>>>(nbr, ws);
  k_scan<<<1,1024,0,stream>>>(ws);
  k_fill<<<192,256,0,stream>>>(nbr, ws);
  k_ww<<<95,256,0,stream>>>(Wrad, W1, W2, ws);
  k_td<<<3072,256,0,stream>>>(aZ, nbr, W3, ws);
  k_tdq<<<1024,256,0,stream>>>(Wq1, Wk1, Wv1, ws);

  k_att<9><<<6144,128,0,stream>>>(nbr, Wb1, ws);
  k_aggo<false><<<1024,256,0,stream>>>(Wo1, bo1, aZ, emb, Wemb, bemb,
                                       Wq2, Wk2, Wv2, ws, nullptr);
  k_att<25><<<6144,128,0,stream>>>(nbr, Wb2, ws);
  k_aggo<true><<<1024,256,0,stream>>>(Wo2, bo2, aZ, emb, Wemb, bemb,
                                      nullptr, nullptr, nullptr, ws, (float*)d_out);
}

// Round 11
// 427.224 us; speedup vs baseline: 1.1471x; 1.1096x over previous
//
#include <hip/hip_runtime.h>
#include <hip/hip_bf16.h>

#define NA 4096
#define NP 49152

typedef _Float16 f16;
typedef _Float16 h2 __attribute__((ext_vector_type(2)));
union U4H { uint4 u; f16 h[8]; h2 p[4]; };

__device__ __forceinline__ float fdot2(h2 a, h2 b, float c){
#if __has_builtin(__builtin_amdgcn_fdot2)
  return __builtin_amdgcn_fdot2(a, b, c, false);
#else
  return c + (float)a.x*(float)b.x + (float)a.y*(float)b.y;
#endif
}

// ---------------- ws layout (float-element offsets) ----------------
constexpr int WS_Y     = 0;
constexpr int WS_G     = 12800;                // 5625 Gaunt tensor
constexpr int WS_NATT  = WS_G + 5632;          // int
constexpr int WS_ATTW  = WS_NATT + 8;          // 1024 floats
constexpr int WS_ATTIJ = WS_ATTW + 1024;       // 1024 ints, sorted by k (i-major inside)
constexpr int WS_TDOFS = WS_ATTIJ + 1024;      // 16 ints
constexpr int WS_TDW   = WS_TDOFS + 16;        // 512 floats
constexpr int WS_TDIJ  = WS_TDW + 512;         // 512 ints
constexpr int WS_AOFS  = WS_TDIJ + 512;        // 32 ints
constexpr int WS_SH    = WS_AOFS + 32;         // NP*9
constexpr int WS_RB    = WS_SH + NP*9;         // NP*16
constexpr int WS_S     = WS_RB + NP*16;        // NP scores (sorted index)
constexpr int WS_CCNT  = WS_S + NP;            // NA ints
constexpr int WS_COFF  = WS_CCNT + NA;         // NA+1 ints
constexpr int WS_CCUR  = WS_COFF + NA + 8;     // NA ints
constexpr int WS_CLST  = WS_CCUR + NA;         // NP ints (pair ids sorted by dst)
constexpr int WS_XQ    = WS_CLST + NP;         // f16 transposed q (NA*800 halves)
constexpr int WS_XK    = WS_XQ + NA*400;
constexpr int WS_XV    = WS_XK + NA*400;
constexpr int WS_PVF   = WS_XV + NA*400;       // f16: td [sp][g][16] (NP*256h); att [sp][400h]
constexpr int WS_WW    = WS_PVF + NP*128;      // 145920 floats (dead after k_td; att pvf may overwrite)
constexpr long long WS_END = (long long)WS_PVF + (long long)NP*256;  // ~76 MB

__device__ const float  GLX[16] = {
  -0.98940093499164993f, -0.94457502307323258f, -0.86563120238783174f, -0.75540440835500303f,
  -0.61787624440264375f, -0.45801677765722739f, -0.28160355077925891f, -0.09501250983763744f,
   0.09501250983763744f,  0.28160355077925891f,  0.45801677765722739f,  0.61787624440264375f,
   0.75540440835500303f,  0.86563120238783174f,  0.94457502307323258f,  0.98940093499164993f };
__device__ const double GLW[16] = {
  0.02715245941175409, 0.06225352393864789, 0.09515851168249278, 0.12462897125553387,
  0.14959598881657673, 0.16915651939500254, 0.18260341504492359, 0.18945061045506850,
  0.18945061045506850, 0.18260341504492359, 0.16915651939500254, 0.14959598881657673,
  0.12462897125553387, 0.09515851168249278, 0.06225352393864789, 0.02715245941175409 };

#define PI_D 3.14159265358979323846

__device__ __forceinline__ float scrub(float v){
  if(!(v == v)) return 0.f;
  return fminf(fmaxf(v, -1e30f), 1e30f);
}

__device__ void real_sph25(float ct, float phi, float* Y){
  float st = sqrtf(fmaxf(0.f, 1.f - ct*ct));
  float P[5][5];
  P[0][0] = 1.f;
  #pragma unroll
  for(int m=1;m<=4;m++) P[m][m] = -(2.f*m - 1.f)*st*P[m-1][m-1];
  #pragma unroll
  for(int m=0;m<4;m++) P[m+1][m] = (2.f*m + 1.f)*ct*P[m][m];
  #pragma unroll
  for(int m=0;m<=4;m++){
    #pragma unroll
    for(int l=m+2;l<=4;l++)
      P[l][m] = ((2.f*l - 1.f)*ct*P[l-1][m] - (float)(l+m-1)*P[l-2][m]) / (float)(l-m);
  }
  const double fact[9] = {1,1,2,6,24,120,720,5040,40320};
  int idx = 0;
  #pragma unroll
  for(int l=0;l<=4;l++){
    #pragma unroll
    for(int m=-l;m<=l;m++){
      int ma = (m < 0) ? -m : m;
      float Nn = (float)sqrt((2*l+1)/(4.0*PI_D)*fact[l-ma]/fact[l+ma]);
      float cs = (ma & 1) ? -1.f : 1.f;
      float v;
      if(m == 0)      v = Nn * P[l][0];
      else if(m > 0)  v = 1.4142135623730951f * Nn * cs * cosf(ma*phi) * P[l][ma];
      else            v = 1.4142135623730951f * Nn * cs * sinf(ma*phi) * P[l][ma];
      Y[idx++] = v;
    }
  }
}

// G kernel: Y recomputed per block; quadrature split 8-way per (i,j,k)
__global__ __launch_bounds__(256) void kq_G(float* ws){
  __shared__ float Ysh[12800];
  int tid = threadIdx.x;
  for(int pt=tid; pt<512; pt+=256){
    float ct  = GLX[pt >> 5];
    float phi = (float)((pt & 31) * (2.0*PI_D/32.0));
    float Y[25];
    real_sph25(ct, phi, Y);
    #pragma unroll
    for(int i=0;i<25;i++) Ysh[pt*25 + i] = Y[i];
  }
  __syncthreads();
  int idx = blockIdx.x*256 + tid;
  int t = idx >> 3, chunk = idx & 7;
  if(t >= 5625) return;
  int k = t % 25, j = (t/25) % 9, i = t/225;
  double acc = 0.0;
  int g0 = chunk*64;
  #pragma unroll 4
  for(int g=g0; g<g0+64; g++){
    double w = GLW[g >> 5] * (2.0*PI_D/32.0);
    acc += w * (double)Ysh[g*25+i] * (double)Ysh[g*25+j] * (double)Ysh[g*25+k];
  }
  acc += __shfl_xor(acc, 1, 8);
  acc += __shfl_xor(acc, 2, 8);
  acc += __shfl_xor(acc, 4, 8);
  if(chunk == 0){
    if(fabs(acc) < 1e-6) acc = 0.0;
    ws[WS_G + (i*9+j)*25 + k] = (float)acc;
  }
}

// list build with LDS-staged G (kills ~225 serial global reads per thread)
__global__ __launch_bounds__(64) void kq_lists(float* ws){
  __shared__ float Gsh[5632];
  __shared__ int cA[25], cT[9], oA[26], oT[10];
  int t = threadIdx.x;
  for(int i=t; i<5625; i+=64) Gsh[i] = ws[WS_G + i];
  __syncthreads();
  const float* G = Gsh;
  if(t < 25){ int c=0; for(int i=0;i<25;i++) for(int j=0;j<9;j++) if(G[(i*9+j)*25+t] != 0.f) c++; cA[t]=c; }
  if(t < 9){  int c=0; for(int i=0;i<9;i++)  for(int j=0;j<9;j++) if(G[(i*9+j)*25+t] != 0.f) c++; cT[t]=c; }
  __syncthreads();
  if(t == 0){
    int s=0; for(int k=0;k<25;k++){ oA[k]=s; s+=cA[k]; } oA[25]=s;
    ((int*)ws)[WS_NATT] = s;
    s=0; for(int k=0;k<9;k++){ oT[k]=s; s+=cT[k]; } oT[9]=s;
  }
  __syncthreads();
  float* attw = ws + WS_ATTW; int* attij = (int*)ws + WS_ATTIJ;
  int* aofs = (int*)ws + WS_AOFS;
  if(t < 26) aofs[t] = oA[t] < 1024 ? oA[t] : 1024;
  if(t < 25){
    int pos = oA[t];
    for(int i=0;i<25;i++) for(int j=0;j<9;j++){
      float w = G[(i*9+j)*25+t];
      if(w != 0.f && pos < 1024){ attw[pos]=w; attij[pos] = i | (j<<5) | (t<<9); pos++; }
    }
  }
  float* tdw = ws + WS_TDW; int* tdij = (int*)ws + WS_TDIJ; int* tdofs = (int*)ws + WS_TDOFS;
  if(t < 9){
    int pos = oT[t];
    for(int i=0;i<9;i++) for(int j=0;j<9;j++){
      float w = G[(i*9+j)*25+t];
      if(w != 0.f && pos < 512){
        int li = (i==0)?0:(i<4)?1:2, lj = (j==0)?0:(j<4)?1:2;
        tdw[pos]=w; tdij[pos] = i | (j<<5) | (li<<10) | (lj<<12); pos++;
      }
    }
    tdofs[t] = oT[t];
    if(t == 0) tdofs[9] = oT[9];
  }
}

// per-pair prep + CSR count (k_cnt folded in)
__global__ void k_pair(const float* disp, const int* nbr, float* ws){
  int p = blockIdx.x*256 + threadIdx.x;
  if(p >= NP) return;
  float dx = disp[3*p], dy = disp[3*p+1], dz = disp[3*p+2];
  float r = sqrtf(dx*dx + dy*dy + dz*dz);
  float inv = 1.f / fmaxf(r, 1e-9f);
  float ux = dx*inv, uy = dy*inv, uz = dz*inv;
  float sh[9];
  sh[0] = 0.28209479177387814f;
  sh[1] = 0.4886025119029199f * uy;
  sh[2] = 0.4886025119029199f * uz;
  sh[3] = 0.4886025119029199f * ux;
  sh[4] = 1.0925484305920792f * ux*uy;
  sh[5] = 1.0925484305920792f * uy*uz;
  sh[6] = 0.31539156525252005f * (3.f*uz*uz - 1.f);
  sh[7] = 1.0925484305920792f * ux*uz;
  sh[8] = 0.5462742152960396f * (ux*ux - uy*uy);
  #pragma unroll
  for(int i=0;i<9;i++) ws[WS_SH + p*9 + i] = scrub(sh[i]);
  float mask = (r < 5.f) ? 1.f : 0.f;
  #pragma unroll
  for(int k=1;k<=16;k++){
    float x  = (float)k * r * 0.2f;
    float px = 3.14159265358979323846f * x;
    float s  = (px < 1e-6f) ? 1.f : (sinf(px)/px);
    ws[WS_RB + p*16 + (k-1)] = scrub(s * mask);
  }
  atomicAdd((int*)ws + WS_CCNT + nbr[2*p], 1);
}

__global__ __launch_bounds__(1024) void k_scan(float* ws){
  __shared__ int part[1024];
  int t = threadIdx.x;
  const int* cnt = (const int*)ws + WS_CCNT;
  int v0 = cnt[4*t], v1 = cnt[4*t+1], v2 = cnt[4*t+2], v3 = cnt[4*t+3];
  part[t] = v0+v1+v2+v3;
  __syncthreads();
  for(int o=1; o<1024; o<<=1){
    int x = (t >= o) ? part[t-o] : 0;
    __syncthreads();
    part[t] += x;
    __syncthreads();
  }
  int base = (t > 0) ? part[t-1] : 0;
  int* offp = (int*)ws + WS_COFF;
  int* cur  = (int*)ws + WS_CCUR;
  offp[4*t]   = base;          cur[4*t]   = base;
  offp[4*t+1] = base+v0;       cur[4*t+1] = base+v0;
  offp[4*t+2] = base+v0+v1;    cur[4*t+2] = base+v0+v1;
  offp[4*t+3] = base+v0+v1+v2; cur[4*t+3] = base+v0+v1+v2;
  if(t == 1023) offp[4096] = part[1023];
}

__global__ void k_fill(const int* nbr, float* ws){
  int p = blockIdx.x*256 + threadIdx.x;
  if(p >= NP) return;
  int d = nbr[2*p];
  int pos = atomicAdd((int*)ws + WS_CCUR + d, 1);
  ((int*)ws)[WS_CLST + pos] = p;
}

// ---------------- WW prefold: WW[s][w][g][d][k] ----------------
__global__ __launch_bounds__(256) void k_ww(const float* Wrad, const float* W1,
                                            const float* W2, float* ws){
  int s = blockIdx.x;
  #pragma unroll
  for(int it=0; it<6; it++){
    int idx = threadIdx.x + 256*it;
    int w = idx / 768, r = idx % 768;
    int d = r / 256, r2 = r % 256, k = r2 / 16, g = r2 % 16;
    const float* Wsrc = (w == 0) ? W1 : W2;
    float acc = 0.f;
    #pragma unroll
    for(int fp=0; fp<16; fp++)
      acc += Wrad[(s*16+k)*16+fp] * Wsrc[(d*16+fp)*16+g];
    ws[WS_WW + ((size_t)(s*2+w)*16 + g)*48 + d*16 + k] = acc;
  }
}

// ---------------- TD phase ----------------
__global__ __launch_bounds__(256) void k_td(const int* aZ, const int* nbr,
    const float* W3, float* ws){
  __shared__ float sh_s[16][9];
  __shared__ float S_s[16][88];
  __shared__ float tp_s[16][9][16];
  int tid = threadIdx.x, pl = tid >> 4, g = tid & 15;
  int sp = blockIdx.x*16 + pl;
  int p = ((const int*)ws)[WS_CLST + sp];
  int src = nbr[2*p+1];
  int Zj = aZ[src];
  {
    float4* S4 = (float4*)&S_s[0][0];
    for(int t0=tid; t0<352; t0+=256) S4[t0] = make_float4(0.f,0.f,0.f,0.f);
  }
  if(g < 9) sh_s[pl][g] = ws[WS_SH + p*9 + g];
  float rb[16];
  {
    const float4* rb4 = (const float4*)(ws + WS_RB + p*16);
    #pragma unroll
    for(int c=0;c<4;c++){
      float4 r = rb4[c];
      rb[4*c]=r.x; rb[4*c+1]=r.y; rb[4*c+2]=r.z; rb[4*c+3]=r.w;
    }
  }
  float A1[3], A2[3];
  {
    const float4* w1 = (const float4*)(ws + WS_WW + ((size_t)(Zj*2+0)*16+g)*48);
    const float4* w2 = (const float4*)(ws + WS_WW + ((size_t)(Zj*2+1)*16+g)*48);
    #pragma unroll
    for(int d=0; d<3; d++){
      float a1 = 0.f, a2 = 0.f;
      #pragma unroll
      for(int c=0;c<4;c++){
        float4 x1 = w1[d*4+c], x2 = w2[d*4+c];
        a1 += x1.x*rb[4*c] + x1.y*rb[4*c+1] + x1.z*rb[4*c+2] + x1.w*rb[4*c+3];
        a2 += x2.x*rb[4*c] + x2.y*rb[4*c+1] + x2.z*rb[4*c+2] + x2.w*rb[4*c+3];
      }
      A1[d] = a1; A2[d] = a2;
    }
  }
  __syncthreads();
  if(g < 9){
    const float* tdw = ws + WS_TDW;
    const int* tdij  = (const int*)ws + WS_TDIJ;
    const int* tdofs = (const int*)ws + WS_TDOFS;
    int e1 = tdofs[g+1];
    for(int e=tdofs[g]; e<e1; e++){
      float w = tdw[e]; int meta = tdij[e];
      int i = meta & 31, j = (meta>>5) & 15, li = (meta>>10) & 3, lj = (meta>>12) & 3;
      S_s[pl][g*9 + li*3 + lj] += w * sh_s[pl][i] * sh_s[pl][j];
    }
  }
  __syncthreads();
  float AA[9];
  #pragma unroll
  for(int li=0;li<3;li++)
    #pragma unroll
    for(int lj=0;lj<3;lj++) AA[li*3+lj] = A1[li]*A2[lj];
  #pragma unroll
  for(int k=0;k<9;k++){
    float tpv = 0.f;
    #pragma unroll
    for(int c=0;c<9;c++) tpv += S_s[pl][k*9+c] * AA[c];
    tp_s[pl][k][g] = tpv;
  }
  __syncthreads();
  float w3r[48];
  #pragma unroll
  for(int d=0;d<3;d++)
    #pragma unroll
    for(int f2=0;f2<16;f2++) w3r[d*16+f2] = W3[(d*16+f2)*16+g];
  float acc9[9];
  #pragma unroll
  for(int k=0;k<9;k++){
    int d = (k==0)?0:(k<4)?1:2;
    const float4* t4 = (const float4*)&tp_s[pl][k][0];
    float acc = 0.f;
    #pragma unroll
    for(int c=0;c<4;c++){
      float4 t = t4[c];
      acc += t.x*w3r[d*16+4*c] + t.y*w3r[d*16+4*c+1] + t.z*w3r[d*16+4*c+2] + t.w*w3r[d*16+4*c+3];
    }
    acc9[k] = scrub(acc);
  }
  f16* ptd = (f16*)(ws + WS_PVF) + (size_t)sp*256 + g*16;
  U4H u0, u1;
  #pragma unroll
  for(int j=0;j<8;j++) u0.h[j] = (f16)acc9[j];
  u1.h[0] = (f16)acc9[8];
  #pragma unroll
  for(int j=1;j<8;j++) u1.h[j] = (f16)0.f;
  *(uint4*)(ptd)     = u0.u;
  *(uint4*)(ptd + 8) = u1.u;
}

// ---------------- fused TD gather + layer-1 QKV (NL=3) ----------------
__global__ __launch_bounds__(256) void k_tdq(const float* Wq, const float* Wk,
                                             const float* Wv, float* ws){
  __shared__ float xsh[4][144];
  __shared__ float wq_sh[768], wk_sh[768], wv_sh[768];
  int tid = threadIdx.x, al = tid >> 6, lane = tid & 63;
  int a = blockIdx.x*4 + al;
  for(int t=tid; t<768; t+=256){ wq_sh[t]=Wq[t]; wk_sh[t]=Wk[t]; wv_sh[t]=Wv[t]; }
  const int* coff = (const int*)ws + WS_COFF;
  int off0 = coff[a], n = coff[a+1] - off0;
  const f16* base = (const f16*)(ws + WS_PVF);
  float acc[8] = {0,0,0,0,0,0,0,0};
  if(lane < 32){
    for(int t=0; t<n; t++){
      U4H u; u.u = *(const uint4*)(base + (size_t)(off0+t)*256 + lane*8);
      #pragma unroll
      for(int j=0;j<8;j++) acc[j] += (float)u.h[j];
    }
  }
  float invn = 1.f / fmaxf((float)n, 1.f);
  if(lane < 32){
    int gg = lane >> 1;
    #pragma unroll
    for(int j=0;j<8;j++){
      int k = (lane & 1)*8 + j;
      if(k < 9) xsh[al][k*16 + gg] = scrub(acc[j]*invn);
    }
  }
  __syncthreads();
  int g = lane & 15, q4 = lane >> 4;
  f16* qt = (f16*)(ws + WS_XQ) + (size_t)a*800 + g*32;
  f16* kt = (f16*)(ws + WS_XK) + (size_t)a*800 + g*32;
  f16* vt = (f16*)(ws + WS_XV) + (size_t)a*800 + g*32;
  for(int i=q4; i<9; i+=4){
    int l = (i==0)?0:(i<4)?1:2;
    float q=0.f, k2=0.f, v2=0.f;
    #pragma unroll
    for(int f2=0;f2<16;f2++){
      float xv = xsh[al][i*16+f2];
      q  += xv*wq_sh[(l*16+f2)*16+g];
      k2 += xv*wk_sh[(l*16+f2)*16+g];
      v2 += xv*wv_sh[(l*16+f2)*16+g];
    }
    qt[i] = (f16)q; kt[i] = (f16)k2; vt[i] = (f16)v2;
  }
}

// ---------------- merged attention (r8-best form: late loads, b128 sweep,
// scatter b16 pvf stores at [sp][400]) --------------------------------------
template<int NI>
__global__ __launch_bounds__(128) void k_att(const int* nbr, const float* Wb, float* ws){
  __shared__ __align__(16) f16 Ml[8][840];   // row stride 32, pl stride 840
  __shared__ float sh_s[8][9];
  constexpr int NPAIR = NI/2;
  constexpr int TAIL  = NI-1;
  int tid = threadIdx.x, pl = tid >> 4, g = tid & 15;
  int sp = blockIdx.x*8 + pl;
  int p = ((const int*)ws)[WS_CLST + sp];
  {
    uint4 z; z.x=0; z.y=0; z.z=0; z.w=0;
    uint4* Mz = (uint4*)&Ml[0][0];
    for(int t0=tid; t0<840; t0+=128) Mz[t0] = z;
  }
  if(g < 9) sh_s[pl][g] = ws[WS_SH + p*9 + g];
  float wbreg[16];
  #pragma unroll
  for(int k=0;k<16;k++) wbreg[k] = Wb[k*16+g];
  __syncthreads();
  {
    const float* attw = ws + WS_ATTW;
    const int* attij  = (const int*)ws + WS_ATTIJ;
    const int* aofs   = (const int*)ws + WS_AOFS;
    for(int kr=g; kr<25; kr+=16){
      f16* Mrow = &Ml[pl][kr*32];
      int e = aofs[kr], e1 = aofs[kr+1];
      int meta = attij[e];
      int curi = meta & 31;
      float cur = 0.f;
      for(; e<e1; e++){
        meta = attij[e];
        int i2 = meta & 31;
        if(i2 != curi){ Mrow[curi] = (f16)cur; cur = 0.f; curi = i2; }
        cur += attw[e] * sh_s[pl][(meta>>5) & 15];
      }
      Mrow[curi] = (f16)cur;
    }
  }
  __syncthreads();
  int dst = nbr[2*p], src = nbr[2*p+1];
  float q_r[NI];
  {
    const f16* qt = (const f16*)(ws + WS_XQ) + (size_t)dst*800 + g*32;
    #pragma unroll
    for(int c=0;c<NPAIR/4;c++){
      U4H u; u.u = *(const uint4*)(qt + c*8);
      #pragma unroll
      for(int j=0;j<8;j++) q_r[c*8+j] = (float)u.h[j];
    }
    q_r[TAIL] = (float)qt[TAIL];
  }
  h2 xk2[NPAIR], xv2[NPAIR];
  float xkT, xvT;
  {
    const f16* kt = (const f16*)(ws + WS_XK) + (size_t)src*800 + g*32;
    const f16* vt = (const f16*)(ws + WS_XV) + (size_t)src*800 + g*32;
    #pragma unroll
    for(int c=0;c<NPAIR/4;c++){
      U4H uk; uk.u = *(const uint4*)(kt + c*8);
      U4H uv; uv.u = *(const uint4*)(vt + c*8);
      #pragma unroll
      for(int j=0;j<4;j++){ xk2[c*4+j] = uk.p[j]; xv2[c*4+j] = uv.p[j]; }
    }
    xkT = (float)kt[TAIL];
    xvT = (float)vt[TAIL];
  }
  float wbf;
  {
    const float4* rb4 = (const float4*)(ws + WS_RB + p*16);
    float acc = 0.f;
    #pragma unroll
    for(int c=0;c<4;c++){
      float4 r = rb4[c];
      acc += r.x*wbreg[4*c] + r.y*wbreg[4*c+1] + r.z*wbreg[4*c+2] + r.w*wbreg[4*c+3];
    }
    wbf = acc;
  }
  f16* pvf = (f16*)(ws + WS_PVF) + (size_t)sp*400;
  float sacc = 0.f;
  #pragma unroll
  for(int k=0;k<25;k++){
    const uint4* Mq = (const uint4*)&Ml[pl][k*32];
    float mT = (float)Ml[pl][k*32 + TAIL];
    float vv = 0.f, kf = 0.f;
    #pragma unroll
    for(int c=0;c<NPAIR/4;c++){
      U4H u; u.u = Mq[c];
      #pragma unroll
      for(int j=0;j<4;j++){
        vv = fdot2(u.p[j], xv2[c*4+j], vv);
        if(k < NI) kf = fdot2(u.p[j], xk2[c*4+j], kf);
      }
    }
    vv += mT * xvT;
    if(k < NI){
      kf += mT * xkT;
      sacc += q_r[k]*kf;
    }
    pvf[k*16 + g] = (f16)scrub(wbf*vv);
  }
  float sl = sacc;
  #pragma unroll
  for(int off=1; off<16; off<<=1) sl += __shfl_xor(sl, off, 16);
  if(g == 0) ws[WS_S + sp] = scrub(sl * 0.05f);   // / sqrt(25*16)
}

// ---------------- fused softmax-gather + output pdense (+QKV next / final) -
template<bool FINAL>
__global__ __launch_bounds__(256) void k_aggo(const float* Wo, const float* bo,
    const int* aZ, const float* emb, const float* Wemb, const float* bemb,
    const float* Wq, const float* Wk, const float* Wv, float* ws, float* out){
  __shared__ float xsh[4][400];
  __shared__ float wo_sh[1280];
  __shared__ float wq_sh[FINAL?4:1280], wk_sh[FINAL?4:1280], wv_sh[FINAL?4:1280];
  __shared__ float osh[FINAL?4:1600];
  int tid = threadIdx.x, al = tid >> 6, lane = tid & 63;
  int a = blockIdx.x*4 + al;
  for(int t=tid; t<1280; t+=256){
    wo_sh[t] = Wo[t];
    if(!FINAL){ wq_sh[t]=Wq[t]; wk_sh[t]=Wk[t]; wv_sh[t]=Wv[t]; }
  }
  const int* coff = (const int*)ws + WS_COFF;
  int off0 = coff[a], n = coff[a+1] - off0;
  float mx = -1e30f;
  for(int t=lane; t<n; t+=64) mx = fmaxf(mx, ws[WS_S + off0 + t]);
  #pragma unroll
  for(int off=1; off<64; off<<=1) mx = fmaxf(mx, __shfl_xor(mx, off));
  float den = 0.f;
  for(int t=lane; t<n; t+=64) den += expf(fminf(ws[WS_S + off0 + t] - mx, 0.f));
  #pragma unroll
  for(int off=1; off<64; off<<=1) den += __shfl_xor(den, off);
  float inv_den = 1.f / (den + 1e-9f);
  float acc[8] = {0,0,0,0,0,0,0,0};
  const f16* base = (const f16*)(ws + WS_PVF);
  for(int t=0; t<n; t++){
    float alpha = expf(fminf(ws[WS_S + off0 + t] - mx, 0.f)) * inv_den;
    if(lane < 50){
      U4H u; u.u = *(const uint4*)(base + (size_t)(off0+t)*400 + lane*8);
      #pragma unroll
      for(int j=0;j<8;j++) acc[j] += alpha * (float)u.h[j];
    }
  }
  if(lane < 50){
    #pragma unroll
    for(int j=0;j<8;j++) xsh[al][lane*8 + j] = scrub(acc[j]);   // flat = k*16+g
  }
  __syncthreads();
  int g = lane & 15, q4 = lane >> 4;
  for(int i=q4; i<25; i+=4){
    int l = (i==0)?0:(i<4)?1:(i<9)?2:(i<16)?3:4;
    float accv = 0.f;
    #pragma unroll
    for(int f2=0;f2<16;f2++) accv += xsh[al][i*16+f2]*wo_sh[(l*16+f2)*16+g];
    if(i == 0){
      accv += bo[g];
      if(FINAL){
        int Z = aZ[a];
        float res = bemb[g];
        #pragma unroll
        for(int e2=0;e2<32;e2++) res += emb[Z*32+e2]*Wemb[e2*16+g];
        accv += res;
      }
    }
    if(FINAL) out[a*400 + i*16 + g] = scrub(accv);
    else      osh[al*400 + i*16 + g] = scrub(accv);
  }
  if(!FINAL){
    __syncthreads();
    f16* qt = (f16*)(ws + WS_XQ) + (size_t)a*800 + g*32;
    f16* kt = (f16*)(ws + WS_XK) + (size_t)a*800 + g*32;
    f16* vt = (f16*)(ws + WS_XV) + (size_t)a*800 + g*32;
    for(int i=q4; i<25; i+=4){
      int l = (i==0)?0:(i<4)?1:(i<9)?2:(i<16)?3:4;
      float q=0.f, k2=0.f, v2=0.f;
      #pragma unroll
      for(int f2=0;f2<16;f2++){
        float xv = osh[al*400 + i*16 + f2];
        q  += xv*wq_sh[(l*16+f2)*16+g];
        k2 += xv*wk_sh[(l*16+f2)*16+g];
        v2 += xv*wv_sh[(l*16+f2)*16+g];
      }
      qt[i] = (f16)q; kt[i] = (f16)k2; vt[i] = (f16)v2;
    }
  }
}

extern "C" void kernel_launch(void* const* d_in, const int* in_sizes, int n_in,
                              void* d_out, int out_size, void* d_ws, size_t ws_size,
                              hipStream_t stream){
  (void)in_sizes; (void)n_in; (void)out_size;
  if(ws_size < (size_t)WS_END * sizeof(float)) return;
  float* ws = (float*)d_ws;
  const int* aZ  = (const int*)d_in[0];
  const int* nbr = (const int*)d_in[1];
  const float* disp = (const float*)d_in[2];
  const float* Wrad = (const float*)d_in[3];
  const float* emb  = (const float*)d_in[4];
  const float* Wemb = (const float*)d_in[5];
  const float* bemb = (const float*)d_in[6];
  const float* W1   = (const float*)d_in[7];
  const float* W2   = (const float*)d_in[8];
  const float* W3   = (const float*)d_in[9];
  const float* Wb1 = (const float*)d_in[10]; const float* Wq1 = (const float*)d_in[11];
  const float* Wk1 = (const float*)d_in[12]; const float* Wv1 = (const float*)d_in[13];
  const float* Wo1 = (const float*)d_in[14]; const float* bo1 = (const float*)d_in[15];
  const float* Wb2 = (const float*)d_in[16]; const float* Wq2 = (const float*)d_in[17];
  const float* Wk2 = (const float*)d_in[18]; const float* Wv2 = (const float*)d_in[19];
  const float* Wo2 = (const float*)d_in[20]; const float* bo2 = (const float*)d_in[21];

  kq_G<<<176,256,0,stream>>>(ws);
  kq_lists<<<1,64,0,stream>>>(ws);
  hipMemsetAsync(ws + WS_CCNT, 0, NA*sizeof(int), stream);
  k_pair<<<192,256,0,stream>>>(disp, nbr, ws);
  k_scan<<<1,1024,0,stream>>>(ws);
  k_fill<<<192,256,0,stream>>>(nbr, ws);
  k_ww<<<95,256,0,stream>>>(Wrad, W1, W2, ws);
  k_td<<<3072,256,0,stream>>>(aZ, nbr, W3, ws);
  k_tdq<<<1024,256,0,stream>>>(Wq1, Wk1, Wv1, ws);

  k_att<9><<<6144,128,0,stream>>>(nbr, Wb1, ws);
  k_aggo<false><<<1024,256,0,stream>>>(Wo1, bo1, aZ, emb, Wemb, bemb,
                                       Wq2, Wk2, Wv2, ws, nullptr);
  k_att<25><<<6144,128,0,stream>>>(nbr, Wb2, ws);
  k_aggo<true><<<1024,256,0,stream>>>(Wo2, bo2, aZ, emb, Wemb, bemb,
                                      nullptr, nullptr, nullptr, ws, (float*)d_out);
}

// Round 12
// 400.128 us; speedup vs baseline: 1.2248x; 1.0677x over previous
//
#include <hip/hip_runtime.h>
#include <hip/hip_bf16.h>

#define NA 4096
#define NP 49152

typedef _Float16 f16;
typedef _Float16 h2 __attribute__((ext_vector_type(2)));
union U4H { uint4 u; f16 h[8]; h2 p[4]; };

__device__ __forceinline__ float fdot2(h2 a, h2 b, float c){
#if __has_builtin(__builtin_amdgcn_fdot2)
  return __builtin_amdgcn_fdot2(a, b, c, false);
#else
  return c + (float)a.x*(float)b.x + (float)a.y*(float)b.y;
#endif
}

// ---------------- ws layout (float-element offsets) ----------------
// i<9-filtered attention list lives in the old (unused) Y region:
constexpr int WS_AOFS9 = 64;                   // 32 ints
constexpr int WS_ATTW9 = 128;                  // 512 floats
constexpr int WS_ATTIJ9= WS_ATTW9 + 512;       // 512 ints
constexpr int WS_G     = 12800;                // 5625 Gaunt tensor
constexpr int WS_NATT  = WS_G + 5632;          // int
constexpr int WS_ATTW  = WS_NATT + 8;          // 1024 floats
constexpr int WS_ATTIJ = WS_ATTW + 1024;       // 1024 ints, sorted by k (i-major inside)
constexpr int WS_TDOFS = WS_ATTIJ + 1024;      // 16 ints
constexpr int WS_TDW   = WS_TDOFS + 16;        // 512 floats
constexpr int WS_TDIJ  = WS_TDW + 512;         // 512 ints
constexpr int WS_AOFS  = WS_TDIJ + 512;        // 32 ints
constexpr int WS_SH    = WS_AOFS + 32;         // NP*9  (SORTED index)
constexpr int WS_RB    = WS_SH + NP*9;         // NP*16 (SORTED index)
constexpr int WS_S     = WS_RB + NP*16;        // NP scores (sorted index)
constexpr int WS_CCNT  = WS_S + NP;            // NA ints
constexpr int WS_COFF  = WS_CCNT + NA;         // NA+1 ints
constexpr int WS_CCUR  = WS_COFF + NA + 8;     // NA ints
constexpr int WS_CLST  = WS_CCUR + NA;         // NP ints (pair ids sorted by dst)
constexpr int WS_XQ    = WS_CLST + NP;         // f16 transposed q (NA*800 halves)
constexpr int WS_XK    = WS_XQ + NA*400;
constexpr int WS_XV    = WS_XK + NA*400;
constexpr int WS_PVF   = WS_XV + NA*400;       // f16: td [sp][g][16]; att [sp][400h]
constexpr int WS_WW    = WS_PVF + NP*128;      // 145920 floats (dead after k_td)
constexpr int WS_PVFE  = WS_PVF + NP*256;      // end of pvf region
constexpr int WS_INV   = WS_PVFE;              // NP ints: p -> sorted pos
constexpr int WS_DS    = WS_INV + NP;          // 2*NP ints: [2*sp]=dst, [2*sp+1]=src
constexpr long long WS_END = (long long)WS_DS + 2*NP + 16;  // ~76.1 MB

__device__ const float  GLX[16] = {
  -0.98940093499164993f, -0.94457502307323258f, -0.86563120238783174f, -0.75540440835500303f,
  -0.61787624440264375f, -0.45801677765722739f, -0.28160355077925891f, -0.09501250983763744f,
   0.09501250983763744f,  0.28160355077925891f,  0.45801677765722739f,  0.61787624440264375f,
   0.75540440835500303f,  0.86563120238783174f,  0.94457502307323258f,  0.98940093499164993f };
__device__ const double GLW[16] = {
  0.02715245941175409, 0.06225352393864789, 0.09515851168249278, 0.12462897125553387,
  0.14959598881657673, 0.16915651939500254, 0.18260341504492359, 0.18945061045506850,
  0.18945061045506850, 0.18260341504492359, 0.16915651939500254, 0.14959598881657673,
  0.12462897125553387, 0.09515851168249278, 0.06225352393864789, 0.02715245941175409 };

#define PI_D 3.14159265358979323846

__device__ __forceinline__ float scrub(float v){
  if(!(v == v)) return 0.f;
  return fminf(fmaxf(v, -1e30f), 1e30f);
}

__device__ void real_sph25(float ct, float phi, float* Y){
  float st = sqrtf(fmaxf(0.f, 1.f - ct*ct));
  float P[5][5];
  P[0][0] = 1.f;
  #pragma unroll
  for(int m=1;m<=4;m++) P[m][m] = -(2.f*m - 1.f)*st*P[m-1][m-1];
  #pragma unroll
  for(int m=0;m<4;m++) P[m+1][m] = (2.f*m + 1.f)*ct*P[m][m];
  #pragma unroll
  for(int m=0;m<=4;m++){
    #pragma unroll
    for(int l=m+2;l<=4;l++)
      P[l][m] = ((2.f*l - 1.f)*ct*P[l-1][m] - (float)(l+m-1)*P[l-2][m]) / (float)(l-m);
  }
  const double fact[9] = {1,1,2,6,24,120,720,5040,40320};
  int idx = 0;
  #pragma unroll
  for(int l=0;l<=4;l++){
    #pragma unroll
    for(int m=-l;m<=l;m++){
      int ma = (m < 0) ? -m : m;
      float Nn = (float)sqrt((2*l+1)/(4.0*PI_D)*fact[l-ma]/fact[l+ma]);
      float cs = (ma & 1) ? -1.f : 1.f;
      float v;
      if(m == 0)      v = Nn * P[l][0];
      else if(m > 0)  v = 1.4142135623730951f * Nn * cs * cosf(ma*phi) * P[l][ma];
      else            v = 1.4142135623730951f * Nn * cs * sinf(ma*phi) * P[l][ma];
      Y[idx++] = v;
    }
  }
}

__global__ __launch_bounds__(256) void kq_G(float* ws){
  __shared__ float Ysh[12800];
  int tid = threadIdx.x;
  for(int pt=tid; pt<512; pt+=256){
    float ct  = GLX[pt >> 5];
    float phi = (float)((pt & 31) * (2.0*PI_D/32.0));
    float Y[25];
    real_sph25(ct, phi, Y);
    #pragma unroll
    for(int i=0;i<25;i++) Ysh[pt*25 + i] = Y[i];
  }
  __syncthreads();
  int idx = blockIdx.x*256 + tid;
  int t = idx >> 3, chunk = idx & 7;
  if(t >= 5625) return;
  int k = t % 25, j = (t/25) % 9, i = t/225;
  double acc = 0.0;
  int g0 = chunk*64;
  #pragma unroll 4
  for(int g=g0; g<g0+64; g++){
    double w = GLW[g >> 5] * (2.0*PI_D/32.0);
    acc += w * (double)Ysh[g*25+i] * (double)Ysh[g*25+j] * (double)Ysh[g*25+k];
  }
  acc += __shfl_xor(acc, 1, 8);
  acc += __shfl_xor(acc, 2, 8);
  acc += __shfl_xor(acc, 4, 8);
  if(chunk == 0){
    if(fabs(acc) < 1e-6) acc = 0.0;
    ws[WS_G + (i*9+j)*25 + k] = (float)acc;
  }
}

// list build (LDS-staged G) + i<9-filtered attention list
__global__ __launch_bounds__(64) void kq_lists(float* ws){
  __shared__ float Gsh[5632];
  __shared__ int cA[25], cT[9], cA9[25], oA[26], oT[10], oA9[26];
  int t = threadIdx.x;
  for(int i=t; i<5625; i+=64) Gsh[i] = ws[WS_G + i];
  __syncthreads();
  const float* G = Gsh;
  if(t < 25){
    int c=0, c9=0;
    for(int i=0;i<25;i++) for(int j=0;j<9;j++) if(G[(i*9+j)*25+t] != 0.f){ c++; if(i<9) c9++; }
    cA[t]=c; cA9[t]=c9;
  }
  if(t < 9){  int c=0; for(int i=0;i<9;i++)  for(int j=0;j<9;j++) if(G[(i*9+j)*25+t] != 0.f) c++; cT[t]=c; }
  __syncthreads();
  if(t == 0){
    int s=0; for(int k=0;k<25;k++){ oA[k]=s; s+=cA[k]; } oA[25]=s;
    ((int*)ws)[WS_NATT] = s;
    s=0; for(int k=0;k<25;k++){ oA9[k]=s; s+=cA9[k]; } oA9[25]=s;
    s=0; for(int k=0;k<9;k++){ oT[k]=s; s+=cT[k]; } oT[9]=s;
  }
  __syncthreads();
  float* attw = ws + WS_ATTW;  int* attij = (int*)ws + WS_ATTIJ;
  float* attw9 = ws + WS_ATTW9; int* attij9 = (int*)ws + WS_ATTIJ9;
  int* aofs  = (int*)ws + WS_AOFS;
  int* aofs9 = (int*)ws + WS_AOFS9;
  if(t < 26){ aofs[t] = oA[t] < 1024 ? oA[t] : 1024; aofs9[t] = oA9[t] < 512 ? oA9[t] : 512; }
  if(t < 25){
    int pos = oA[t], pos9 = oA9[t];
    for(int i=0;i<25;i++) for(int j=0;j<9;j++){
      float w = G[(i*9+j)*25+t];
      if(w != 0.f){
        if(pos < 1024){ attw[pos]=w; attij[pos] = i | (j<<5) | (t<<9); pos++; }
        if(i < 9 && pos9 < 512){ attw9[pos9]=w; attij9[pos9] = i | (j<<5) | (t<<9); pos9++; }
      }
    }
  }
  float* tdw = ws + WS_TDW; int* tdij = (int*)ws + WS_TDIJ; int* tdofs = (int*)ws + WS_TDOFS;
  if(t < 9){
    int pos = oT[t];
    for(int i=0;i<9;i++) for(int j=0;j<9;j++){
      float w = G[(i*9+j)*25+t];
      if(w != 0.f && pos < 512){
        int li = (i==0)?0:(i<4)?1:2, lj = (j==0)?0:(j<4)?1:2;
        tdw[pos]=w; tdij[pos] = i | (j<<5) | (li<<10) | (lj<<12); pos++;
      }
    }
    tdofs[t] = oT[t];
    if(t == 0) tdofs[9] = oT[9];
  }
}

// ---------------- CSR by dst ----------------
__global__ void k_cnt(const int* nbr, float* ws){
  int p = blockIdx.x*256 + threadIdx.x;
  if(p >= NP) return;
  atomicAdd((int*)ws + WS_CCNT + nbr[2*p], 1);
}

__global__ __launch_bounds__(1024) void k_scan(float* ws){
  __shared__ int part[1024];
  int t = threadIdx.x;
  const int* cnt = (const int*)ws + WS_CCNT;
  int v0 = cnt[4*t], v1 = cnt[4*t+1], v2 = cnt[4*t+2], v3 = cnt[4*t+3];
  part[t] = v0+v1+v2+v3;
  __syncthreads();
  for(int o=1; o<1024; o<<=1){
    int x = (t >= o) ? part[t-o] : 0;
    __syncthreads();
    part[t] += x;
    __syncthreads();
  }
  int base = (t > 0) ? part[t-1] : 0;
  int* offp = (int*)ws + WS_COFF;
  int* cur  = (int*)ws + WS_CCUR;
  offp[4*t]   = base;          cur[4*t]   = base;
  offp[4*t+1] = base+v0;       cur[4*t+1] = base+v0;
  offp[4*t+2] = base+v0+v1;    cur[4*t+2] = base+v0+v1;
  offp[4*t+3] = base+v0+v1+v2; cur[4*t+3] = base+v0+v1+v2;
  if(t == 1023) offp[4096] = part[1023];
}

// fill: clst + inverse permutation + sorted dst/src
__global__ void k_fill(const int* nbr, float* ws){
  int p = blockIdx.x*256 + threadIdx.x;
  if(p >= NP) return;
  int d = nbr[2*p], s = nbr[2*p+1];
  int pos = atomicAdd((int*)ws + WS_CCUR + d, 1);
  ((int*)ws)[WS_CLST + pos] = p;
  ((int*)ws)[WS_INV + p] = pos;
  ((int*)ws)[WS_DS + 2*pos]     = d;
  ((int*)ws)[WS_DS + 2*pos + 1] = s;
}

// per-pair prep, writes sh/rb at SORTED index (runs after k_fill)
__global__ void k_pair(const float* disp, float* ws){
  int p = blockIdx.x*256 + threadIdx.x;
  if(p >= NP) return;
  int sp = ((const int*)ws)[WS_INV + p];
  float dx = disp[3*p], dy = disp[3*p+1], dz = disp[3*p+2];
  float r = sqrtf(dx*dx + dy*dy + dz*dz);
  float inv = 1.f / fmaxf(r, 1e-9f);
  float ux = dx*inv, uy = dy*inv, uz = dz*inv;
  float sh[9];
  sh[0] = 0.28209479177387814f;
  sh[1] = 0.4886025119029199f * uy;
  sh[2] = 0.4886025119029199f * uz;
  sh[3] = 0.4886025119029199f * ux;
  sh[4] = 1.0925484305920792f * ux*uy;
  sh[5] = 1.0925484305920792f * uy*uz;
  sh[6] = 0.31539156525252005f * (3.f*uz*uz - 1.f);
  sh[7] = 1.0925484305920792f * ux*uz;
  sh[8] = 0.5462742152960396f * (ux*ux - uy*uy);
  #pragma unroll
  for(int i=0;i<9;i++) ws[WS_SH + sp*9 + i] = scrub(sh[i]);
  float mask = (r < 5.f) ? 1.f : 0.f;
  float rbv[16];
  #pragma unroll
  for(int k=1;k<=16;k++){
    float x  = (float)k * r * 0.2f;
    float px = 3.14159265358979323846f * x;
    float s  = (px < 1e-6f) ? 1.f : (sinf(px)/px);
    rbv[k-1] = scrub(s * mask);
  }
  float4* rb4 = (float4*)(ws + WS_RB + sp*16);
  #pragma unroll
  for(int c=0;c<4;c++) rb4[c] = make_float4(rbv[4*c], rbv[4*c+1], rbv[4*c+2], rbv[4*c+3]);
}

// ---------------- WW prefold: WW[s][w][g][d][k] ----------------
__global__ __launch_bounds__(256) void k_ww(const float* Wrad, const float* W1,
                                            const float* W2, float* ws){
  int s = blockIdx.x;
  #pragma unroll
  for(int it=0; it<6; it++){
    int idx = threadIdx.x + 256*it;
    int w = idx / 768, r = idx % 768;
    int d = r / 256, r2 = r % 256, k = r2 / 16, g = r2 % 16;
    const float* Wsrc = (w == 0) ? W1 : W2;
    float acc = 0.f;
    #pragma unroll
    for(int fp=0; fp<16; fp++)
      acc += Wrad[(s*16+k)*16+fp] * Wsrc[(d*16+fp)*16+g];
    ws[WS_WW + ((size_t)(s*2+w)*16 + g)*48 + d*16 + k] = acc;
  }
}

// ---------------- TD phase (sorted-index reads) ----------------
__global__ __launch_bounds__(256) void k_td(const int* aZ, const float* W3, float* ws){
  __shared__ float sh_s[16][9];
  __shared__ float S_s[16][88];
  __shared__ float tp_s[16][9][16];
  int tid = threadIdx.x, pl = tid >> 4, g = tid & 15;
  int sp = blockIdx.x*16 + pl;
  int src = ((const int*)ws)[WS_DS + 2*sp + 1];
  int Zj = aZ[src];
  {
    float4* S4 = (float4*)&S_s[0][0];
    for(int t0=tid; t0<352; t0+=256) S4[t0] = make_float4(0.f,0.f,0.f,0.f);
  }
  if(g < 9) sh_s[pl][g] = ws[WS_SH + sp*9 + g];
  float rb[16];
  {
    const float4* rb4 = (const float4*)(ws + WS_RB + sp*16);
    #pragma unroll
    for(int c=0;c<4;c++){
      float4 r = rb4[c];
      rb[4*c]=r.x; rb[4*c+1]=r.y; rb[4*c+2]=r.z; rb[4*c+3]=r.w;
    }
  }
  float A1[3], A2[3];
  {
    const float4* w1 = (const float4*)(ws + WS_WW + ((size_t)(Zj*2+0)*16+g)*48);
    const float4* w2 = (const float4*)(ws + WS_WW + ((size_t)(Zj*2+1)*16+g)*48);
    #pragma unroll
    for(int d=0; d<3; d++){
      float a1 = 0.f, a2 = 0.f;
      #pragma unroll
      for(int c=0;c<4;c++){
        float4 x1 = w1[d*4+c], x2 = w2[d*4+c];
        a1 += x1.x*rb[4*c] + x1.y*rb[4*c+1] + x1.z*rb[4*c+2] + x1.w*rb[4*c+3];
        a2 += x2.x*rb[4*c] + x2.y*rb[4*c+1] + x2.z*rb[4*c+2] + x2.w*rb[4*c+3];
      }
      A1[d] = a1; A2[d] = a2;
    }
  }
  __syncthreads();
  if(g < 9){
    const float* tdw = ws + WS_TDW;
    const int* tdij  = (const int*)ws + WS_TDIJ;
    const int* tdofs = (const int*)ws + WS_TDOFS;
    int e1 = tdofs[g+1];
    for(int e=tdofs[g]; e<e1; e++){
      float w = tdw[e]; int meta = tdij[e];
      int i = meta & 31, j = (meta>>5) & 15, li = (meta>>10) & 3, lj = (meta>>12) & 3;
      S_s[pl][g*9 + li*3 + lj] += w * sh_s[pl][i] * sh_s[pl][j];
    }
  }
  __syncthreads();
  float AA[9];
  #pragma unroll
  for(int li=0;li<3;li++)
    #pragma unroll
    for(int lj=0;lj<3;lj++) AA[li*3+lj] = A1[li]*A2[lj];
  #pragma unroll
  for(int k=0;k<9;k++){
    float tpv = 0.f;
    #pragma unroll
    for(int c=0;c<9;c++) tpv += S_s[pl][k*9+c] * AA[c];
    tp_s[pl][k][g] = tpv;
  }
  __syncthreads();
  float w3r[48];
  #pragma unroll
  for(int d=0;d<3;d++)
    #pragma unroll
    for(int f2=0;f2<16;f2++) w3r[d*16+f2] = W3[(d*16+f2)*16+g];
  float acc9[9];
  #pragma unroll
  for(int k=0;k<9;k++){
    int d = (k==0)?0:(k<4)?1:2;
    const float4* t4 = (const float4*)&tp_s[pl][k][0];
    float acc = 0.f;
    #pragma unroll
    for(int c=0;c<4;c++){
      float4 t = t4[c];
      acc += t.x*w3r[d*16+4*c] + t.y*w3r[d*16+4*c+1] + t.z*w3r[d*16+4*c+2] + t.w*w3r[d*16+4*c+3];
    }
    acc9[k] = scrub(acc);
  }
  f16* ptd = (f16*)(ws + WS_PVF) + (size_t)sp*256 + g*16;
  U4H u0, u1;
  #pragma unroll
  for(int j=0;j<8;j++) u0.h[j] = (f16)acc9[j];
  u1.h[0] = (f16)acc9[8];
  #pragma unroll
  for(int j=1;j<8;j++) u1.h[j] = (f16)0.f;
  *(uint4*)(ptd)     = u0.u;
  *(uint4*)(ptd + 8) = u1.u;
}

// ---------------- fused TD gather + layer-1 QKV (NL=3) ----------------
__global__ __launch_bounds__(256) void k_tdq(const float* Wq, const float* Wk,
                                             const float* Wv, float* ws){
  __shared__ float xsh[4][144];
  __shared__ float wq_sh[768], wk_sh[768], wv_sh[768];
  int tid = threadIdx.x, al = tid >> 6, lane = tid & 63;
  int a = blockIdx.x*4 + al;
  for(int t=tid; t<768; t+=256){ wq_sh[t]=Wq[t]; wk_sh[t]=Wk[t]; wv_sh[t]=Wv[t]; }
  const int* coff = (const int*)ws + WS_COFF;
  int off0 = coff[a], n = coff[a+1] - off0;
  const f16* base = (const f16*)(ws + WS_PVF);
  float acc[8] = {0,0,0,0,0,0,0,0};
  if(lane < 32){
    for(int t=0; t<n; t++){
      U4H u; u.u = *(const uint4*)(base + (size_t)(off0+t)*256 + lane*8);
      #pragma unroll
      for(int j=0;j<8;j++) acc[j] += (float)u.h[j];
    }
  }
  float invn = 1.f / fmaxf((float)n, 1.f);
  if(lane < 32){
    int gg = lane >> 1;
    #pragma unroll
    for(int j=0;j<8;j++){
      int k = (lane & 1)*8 + j;
      if(k < 9) xsh[al][k*16 + gg] = scrub(acc[j]*invn);
    }
  }
  __syncthreads();
  int g = lane & 15, q4 = lane >> 4;
  f16* qt = (f16*)(ws + WS_XQ) + (size_t)a*800 + g*32;
  f16* kt = (f16*)(ws + WS_XK) + (size_t)a*800 + g*32;
  f16* vt = (f16*)(ws + WS_XV) + (size_t)a*800 + g*32;
  for(int i=q4; i<9; i+=4){
    int l = (i==0)?0:(i<4)?1:2;
    float q=0.f, k2=0.f, v2=0.f;
    #pragma unroll
    for(int f2=0;f2<16;f2++){
      float xv = xsh[al][i*16+f2];
      q  += xv*wq_sh[(l*16+f2)*16+g];
      k2 += xv*wk_sh[(l*16+f2)*16+g];
      v2 += xv*wv_sh[(l*16+f2)*16+g];
    }
    qt[i] = (f16)q; kt[i] = (f16)k2; vt[i] = (f16)v2;
  }
}

// ---------------- merged attention (r11-best form + sorted reads,
// NI=9 uses i<9-filtered list with compact 16-half M rows) ------------------
template<int NI>
__global__ __launch_bounds__(128) void k_att(const float* Wb, float* ws){
  constexpr int MROWH = (NI == 9) ? 16 : 32;    // halves per M row
  constexpr int PLSTR = (NI == 9) ? 408 : 840;  // pl stride (bank spread)
  __shared__ __align__(16) f16 Ml[8][PLSTR];
  __shared__ float sh_s[8][9];
  __shared__ float wb_sh[256];
  constexpr int NPAIR = NI/2;
  constexpr int TAIL  = NI-1;
  int tid = threadIdx.x, pl = tid >> 4, g = tid & 15;
  int sp = blockIdx.x*8 + pl;
  {
    uint4 z; z.x=0; z.y=0; z.z=0; z.w=0;
    uint4* Mz = (uint4*)&Ml[0][0];
    for(int t0=tid; t0<PLSTR; t0+=128) Mz[t0] = z;
  }
  for(int t0=tid; t0<256; t0+=128) wb_sh[t0] = Wb[t0];
  if(g < 9) sh_s[pl][g] = ws[WS_SH + sp*9 + g];
  __syncthreads();
  {
    const float* attw = ws + (NI==9 ? WS_ATTW9 : WS_ATTW);
    const int* attij  = (const int*)ws + (NI==9 ? WS_ATTIJ9 : WS_ATTIJ);
    const int* aofs   = (const int*)ws + (NI==9 ? WS_AOFS9 : WS_AOFS);
    for(int kr=g; kr<25; kr+=16){
      f16* Mrow = &Ml[pl][kr*MROWH];
      int e = aofs[kr], e1 = aofs[kr+1];
      if(e < e1){
        int meta = attij[e];
        int curi = meta & 31;
        float cur = 0.f;
        for(; e<e1; e++){
          meta = attij[e];
          int i2 = meta & 31;
          if(i2 != curi){ Mrow[curi] = (f16)cur; cur = 0.f; curi = i2; }
          cur += attw[e] * sh_s[pl][(meta>>5) & 15];
        }
        Mrow[curi] = (f16)cur;
      }
    }
  }
  __syncthreads();
  int dst = ((const int*)ws)[WS_DS + 2*sp];
  int src = ((const int*)ws)[WS_DS + 2*sp + 1];
  float q_r[NI];
  {
    const f16* qt = (const f16*)(ws + WS_XQ) + (size_t)dst*800 + g*32;
    #pragma unroll
    for(int c=0;c<NPAIR/4;c++){
      U4H u; u.u = *(const uint4*)(qt + c*8);
      #pragma unroll
      for(int j=0;j<8;j++) q_r[c*8+j] = (float)u.h[j];
    }
    q_r[TAIL] = (float)qt[TAIL];
  }
  h2 xk2[NPAIR], xv2[NPAIR];
  float xkT, xvT;
  {
    const f16* kt = (const f16*)(ws + WS_XK) + (size_t)src*800 + g*32;
    const f16* vt = (const f16*)(ws + WS_XV) + (size_t)src*800 + g*32;
    #pragma unroll
    for(int c=0;c<NPAIR/4;c++){
      U4H uk; uk.u = *(const uint4*)(kt + c*8);
      U4H uv; uv.u = *(const uint4*)(vt + c*8);
      #pragma unroll
      for(int j=0;j<4;j++){ xk2[c*4+j] = uk.p[j]; xv2[c*4+j] = uv.p[j]; }
    }
    xkT = (float)kt[TAIL];
    xvT = (float)vt[TAIL];
  }
  float wbf;
  {
    const float4* rb4 = (const float4*)(ws + WS_RB + sp*16);
    float acc = 0.f;
    #pragma unroll
    for(int c=0;c<4;c++){
      float4 r = rb4[c];
      acc += r.x*wb_sh[(4*c)*16+g] + r.y*wb_sh[(4*c+1)*16+g]
           + r.z*wb_sh[(4*c+2)*16+g] + r.w*wb_sh[(4*c+3)*16+g];
    }
    wbf = acc;
  }
  f16* pvf = (f16*)(ws + WS_PVF) + (size_t)sp*400;
  float sacc = 0.f;
  #pragma unroll
  for(int k=0;k<25;k++){
    const uint4* Mq = (const uint4*)&Ml[pl][k*MROWH];
    float mT = (float)Ml[pl][k*MROWH + TAIL];
    float vv = 0.f, kf = 0.f;
    #pragma unroll
    for(int c=0;c<NPAIR/4;c++){
      U4H u; u.u = Mq[c];
      #pragma unroll
      for(int j=0;j<4;j++){
        vv = fdot2(u.p[j], xv2[c*4+j], vv);
        if(k < NI) kf = fdot2(u.p[j], xk2[c*4+j], kf);
      }
    }
    vv += mT * xvT;
    if(k < NI){
      kf += mT * xkT;
      sacc += q_r[k]*kf;
    }
    pvf[k*16 + g] = (f16)scrub(wbf*vv);
  }
  float sl = sacc;
  #pragma unroll
  for(int off=1; off<16; off<<=1) sl += __shfl_xor(sl, off, 16);
  if(g == 0) ws[WS_S + sp] = scrub(sl * 0.05f);   // / sqrt(25*16)
}

// ---------------- fused softmax-gather + output pdense (+QKV next / final) -
template<bool FINAL>
__global__ __launch_bounds__(256) void k_aggo(const float* Wo, const float* bo,
    const int* aZ, const float* emb, const float* Wemb, const float* bemb,
    const float* Wq, const float* Wk, const float* Wv, float* ws, float* out){
  __shared__ float xsh[4][400];
  __shared__ float wo_sh[1280];
  __shared__ float wq_sh[FINAL?4:1280], wk_sh[FINAL?4:1280], wv_sh[FINAL?4:1280];
  __shared__ float osh[FINAL?4:1600];
  int tid = threadIdx.x, al = tid >> 6, lane = tid & 63;
  int a = blockIdx.x*4 + al;
  for(int t=tid; t<1280; t+=256){
    wo_sh[t] = Wo[t];
    if(!FINAL){ wq_sh[t]=Wq[t]; wk_sh[t]=Wk[t]; wv_sh[t]=Wv[t]; }
  }
  const int* coff = (const int*)ws + WS_COFF;
  int off0 = coff[a], n = coff[a+1] - off0;
  float mx = -1e30f;
  for(int t=lane; t<n; t+=64) mx = fmaxf(mx, ws[WS_S + off0 + t]);
  #pragma unroll
  for(int off=1; off<64; off<<=1) mx = fmaxf(mx, __shfl_xor(mx, off));
  float den = 0.f;
  for(int t=lane; t<n; t+=64) den += expf(fminf(ws[WS_S + off0 + t] - mx, 0.f));
  #pragma unroll
  for(int off=1; off<64; off<<=1) den += __shfl_xor(den, off);
  float inv_den = 1.f / (den + 1e-9f);
  float acc[8] = {0,0,0,0,0,0,0,0};
  const f16* base = (const f16*)(ws + WS_PVF);
  for(int t=0; t<n; t++){
    float alpha = expf(fminf(ws[WS_S + off0 + t] - mx, 0.f)) * inv_den;
    if(lane < 50){
      U4H u; u.u = *(const uint4*)(base + (size_t)(off0+t)*400 + lane*8);
      #pragma unroll
      for(int j=0;j<8;j++) acc[j] += alpha * (float)u.h[j];
    }
  }
  if(lane < 50){
    #pragma unroll
    for(int j=0;j<8;j++) xsh[al][lane*8 + j] = scrub(acc[j]);   // flat = k*16+g
  }
  __syncthreads();
  int g = lane & 15, q4 = lane >> 4;
  for(int i=q4; i<25; i+=4){
    int l = (i==0)?0:(i<4)?1:(i<9)?2:(i<16)?3:4;
    float accv = 0.f;
    #pragma unroll
    for(int f2=0;f2<16;f2++) accv += xsh[al][i*16+f2]*wo_sh[(l*16+f2)*16+g];
    if(i == 0){
      accv += bo[g];
      if(FINAL){
        int Z = aZ[a];
        float res = bemb[g];
        #pragma unroll
        for(int e2=0;e2<32;e2++) res += emb[Z*32+e2]*Wemb[e2*16+g];
        accv += res;
      }
    }
    if(FINAL) out[a*400 + i*16 + g] = scrub(accv);
    else      osh[al*400 + i*16 + g] = scrub(accv);
  }
  if(!FINAL){
    __syncthreads();
    f16* qt = (f16*)(ws + WS_XQ) + (size_t)a*800 + g*32;
    f16* kt = (f16*)(ws + WS_XK) + (size_t)a*800 + g*32;
    f16* vt = (f16*)(ws + WS_XV) + (size_t)a*800 + g*32;
    for(int i=q4; i<25; i+=4){
      int l = (i==0)?0:(i<4)?1:(i<9)?2:(i<16)?3:4;
      float q=0.f, k2=0.f, v2=0.f;
      #pragma unroll
      for(int f2=0;f2<16;f2++){
        float xv = osh[al*400 + i*16 + f2];
        q  += xv*wq_sh[(l*16+f2)*16+g];
        k2 += xv*wk_sh[(l*16+f2)*16+g];
        v2 += xv*wv_sh[(l*16+f2)*16+g];
      }
      qt[i] = (f16)q; kt[i] = (f16)k2; vt[i] = (f16)v2;
    }
  }
}

extern "C" void kernel_launch(void* const* d_in, const int* in_sizes, int n_in,
                              void* d_out, int out_size, void* d_ws, size_t ws_size,
                              hipStream_t stream){
  (void)in_sizes; (void)n_in; (void)out_size;
  if(ws_size < (size_t)WS_END * sizeof(float)) return;
  float* ws = (float*)d_ws;
  const int* aZ  = (const int*)d_in[0];
  const int* nbr = (const int*)d_in[1];
  const float* disp = (const float*)d_in[2];
  const float* Wrad = (const float*)d_in[3];
  const float* emb  = (const float*)d_in[4];
  const float* Wemb = (const float*)d_in[5];
  const float* bemb = (const float*)d_in[6];
  const float* W1   = (const float*)d_in[7];
  const float* W2   = (const float*)d_in[8];
  const float* W3   = (const float*)d_in[9];
  const float* Wb1 = (const float*)d_in[10]; const float* Wq1 = (const float*)d_in[11];
  const float* Wk1 = (const float*)d_in[12]; const float* Wv1 = (const float*)d_in[13];
  const float* Wo1 = (const float*)d_in[14]; const float* bo1 = (const float*)d_in[15];
  const float* Wb2 = (const float*)d_in[16]; const float* Wq2 = (const float*)d_in[17];
  const float* Wk2 = (const float*)d_in[18]; const float* Wv2 = (const float*)d_in[19];
  const float* Wo2 = (const float*)d_in[20]; const float* bo2 = (const float*)d_in[21];

  kq_G<<<176,256,0,stream>>>(ws);
  kq_lists<<<1,64,0,stream>>>(ws);
  hipMemsetAsync(ws + WS_CCNT, 0, NA*sizeof(int), stream);
  k_cnt<<<192,256,0,stream>>>(nbr, ws);
  k_scan<<<1,1024,0,stream>>>(ws);
  k_fill<<<192,256,0,stream>>>(nbr, ws);
  k_pair<<<192,256,0,stream>>>(disp, ws);
  k_ww<<<95,256,0,stream>>>(Wrad, W1, W2, ws);
  k_td<<<3072,256,0,stream>>>(aZ, W3, ws);
  k_tdq<<<1024,256,0,stream>>>(Wq1, Wk1, Wv1, ws);

  k_att<9><<<6144,128,0,stream>>>(Wb1, ws);
  k_aggo<false><<<1024,256,0,stream>>>(Wo1, bo1, aZ, emb, Wemb, bemb,
                                       Wq2, Wk2, Wv2, ws, nullptr);
  k_att<25><<<6144,128,0,stream>>>(Wb2, ws);
  k_aggo<true><<<1024,256,0,stream>>>(Wo2, bo2, aZ, emb, Wemb, bemb,
                                      nullptr, nullptr, nullptr, ws, (float*)d_out);
}

// Round 13
// 390.348 us; speedup vs baseline: 1.2554x; 1.0251x over previous
//
#include <hip/hip_runtime.h>
#include <hip/hip_bf16.h>

#define NA 4096
#define NP 49152

typedef _Float16 f16;
typedef _Float16 h2 __attribute__((ext_vector_type(2)));
union U4H { uint4 u; f16 h[8]; h2 p[4]; };

__device__ __forceinline__ float fdot2(h2 a, h2 b, float c){
#if __has_builtin(__builtin_amdgcn_fdot2)
  return __builtin_amdgcn_fdot2(a, b, c, false);
#else
  return c + (float)a.x*(float)b.x + (float)a.y*(float)b.y;
#endif
}

// ---------------- ws layout (float-element offsets) ----------------
constexpr int WS_AOFS9 = 64;                   // 32 ints
constexpr int WS_ATTW9 = 128;                  // 512 floats
constexpr int WS_ATTIJ9= WS_ATTW9 + 512;       // 512 ints
constexpr int WS_G     = 12800;                // 5625 Gaunt tensor
constexpr int WS_NATT  = WS_G + 5632;          // int
constexpr int WS_ATTW  = WS_NATT + 8;          // 1024 floats
constexpr int WS_ATTIJ = WS_ATTW + 1024;       // 1024 ints (sorted by k, i-major)
constexpr int WS_TDOFS = WS_ATTIJ + 1024;      // 16 ints
constexpr int WS_TDW   = WS_TDOFS + 16;        // 512 floats
constexpr int WS_TDIJ  = WS_TDW + 512;         // 512 ints
constexpr int WS_AOFS  = WS_TDIJ + 512;        // 32 ints
constexpr int WS_SH    = WS_AOFS + 32;         // NP*9  (SORTED index)
constexpr int WS_RB    = WS_SH + NP*9;         // NP*16 (SORTED index)
constexpr int WS_S     = WS_RB + NP*16;        // NP scores (sorted index)
constexpr int WS_CCNT  = WS_S + NP;            // NA ints
constexpr int WS_COFF  = WS_CCNT + NA;         // NA+1 ints
constexpr int WS_CCUR  = WS_COFF + NA + 8;     // NA ints
constexpr int WS_CLST  = WS_CCUR + NA;         // (unused, kept for layout)
constexpr int WS_XQ    = WS_CLST + NP;         // f16 transposed q (NA*800 halves)
constexpr int WS_XK    = WS_XQ + NA*400;
constexpr int WS_XV    = WS_XK + NA*400;
constexpr int WS_PVF   = WS_XV + NA*400;       // f16: td [sp][g][16]; att [sp][400h]
constexpr int WS_WW    = WS_PVF + NP*128;      // 145920 floats (dead after k_td)
constexpr int WS_PVFE  = WS_PVF + NP*256;
constexpr int WS_DS    = WS_PVFE;              // 2*NP ints: [2*sp]=dst, [2*sp+1]=src
constexpr long long WS_END = (long long)WS_DS + 2*NP + 16;  // ~76 MB

__device__ const float  GLX[16] = {
  -0.98940093499164993f, -0.94457502307323258f, -0.86563120238783174f, -0.75540440835500303f,
  -0.61787624440264375f, -0.45801677765722739f, -0.28160355077925891f, -0.09501250983763744f,
   0.09501250983763744f,  0.28160355077925891f,  0.45801677765722739f,  0.61787624440264375f,
   0.75540440835500303f,  0.86563120238783174f,  0.94457502307323258f,  0.98940093499164993f };
__device__ const double GLW[16] = {
  0.02715245941175409, 0.06225352393864789, 0.09515851168249278, 0.12462897125553387,
  0.14959598881657673, 0.16915651939500254, 0.18260341504492359, 0.18945061045506850,
  0.18945061045506850, 0.18260341504492359, 0.16915651939500254, 0.14959598881657673,
  0.12462897125553387, 0.09515851168249278, 0.06225352393864789, 0.02715245941175409 };

#define PI_D 3.14159265358979323846

__device__ __forceinline__ float scrub(float v){
  if(!(v == v)) return 0.f;
  return fminf(fmaxf(v, -1e30f), 1e30f);
}

__device__ void real_sph25(float ct, float phi, float* Y){
  float st = sqrtf(fmaxf(0.f, 1.f - ct*ct));
  float P[5][5];
  P[0][0] = 1.f;
  #pragma unroll
  for(int m=1;m<=4;m++) P[m][m] = -(2.f*m - 1.f)*st*P[m-1][m-1];
  #pragma unroll
  for(int m=0;m<4;m++) P[m+1][m] = (2.f*m + 1.f)*ct*P[m][m];
  #pragma unroll
  for(int m=0;m<=4;m++){
    #pragma unroll
    for(int l=m+2;l<=4;l++)
      P[l][m] = ((2.f*l - 1.f)*ct*P[l-1][m] - (float)(l+m-1)*P[l-2][m]) / (float)(l-m);
  }
  const double fact[9] = {1,1,2,6,24,120,720,5040,40320};
  int idx = 0;
  #pragma unroll
  for(int l=0;l<=4;l++){
    #pragma unroll
    for(int m=-l;m<=l;m++){
      int ma = (m < 0) ? -m : m;
      float Nn = (float)sqrt((2*l+1)/(4.0*PI_D)*fact[l-ma]/fact[l+ma]);
      float cs = (ma & 1) ? -1.f : 1.f;
      float v;
      if(m == 0)      v = Nn * P[l][0];
      else if(m > 0)  v = 1.4142135623730951f * Nn * cs * cosf(ma*phi) * P[l][ma];
      else            v = 1.4142135623730951f * Nn * cs * sinf(ma*phi) * P[l][ma];
      Y[idx++] = v;
    }
  }
}

// ---------------- u1: {quadrature G | WW prefold | CSR count} --------------
__global__ __launch_bounds__(256) void k_u1(const float* Wrad, const float* W1,
    const float* W2, const int* nbr, float* ws){
  __shared__ float Ysh[12800];
  int b = blockIdx.x, tid = threadIdx.x;
  if(b < 176){
    for(int pt=tid; pt<512; pt+=256){
      float ct  = GLX[pt >> 5];
      float phi = (float)((pt & 31) * (2.0*PI_D/32.0));
      float Y[25];
      real_sph25(ct, phi, Y);
      #pragma unroll
      for(int i=0;i<25;i++) Ysh[pt*25 + i] = Y[i];
    }
    __syncthreads();
    int idx = b*256 + tid;
    int t = idx >> 3, chunk = idx & 7;
    if(t >= 5625) return;
    int k = t % 25, j = (t/25) % 9, i = t/225;
    double acc = 0.0;
    int g0 = chunk*64;
    #pragma unroll 4
    for(int g=g0; g<g0+64; g++){
      double w = GLW[g >> 5] * (2.0*PI_D/32.0);
      acc += w * (double)Ysh[g*25+i] * (double)Ysh[g*25+j] * (double)Ysh[g*25+k];
    }
    acc += __shfl_xor(acc, 1, 8);
    acc += __shfl_xor(acc, 2, 8);
    acc += __shfl_xor(acc, 4, 8);
    if(chunk == 0){
      if(fabs(acc) < 1e-6) acc = 0.0;
      ws[WS_G + (i*9+j)*25 + k] = (float)acc;
    }
  } else if(b < 271){
    int s = b - 176;
    #pragma unroll
    for(int it=0; it<6; it++){
      int idx = tid + 256*it;
      int w = idx / 768, r = idx % 768;
      int d = r / 256, r2 = r % 256, k = r2 / 16, g = r2 % 16;
      const float* Wsrc = (w == 0) ? W1 : W2;
      float acc = 0.f;
      #pragma unroll
      for(int fp=0; fp<16; fp++)
        acc += Wrad[(s*16+k)*16+fp] * Wsrc[(d*16+fp)*16+g];
      ws[WS_WW + ((size_t)(s*2+w)*16 + g)*48 + d*16 + k] = acc;
    }
  } else {
    int p = (b-271)*256 + tid;
    if(p < NP) atomicAdd((int*)ws + WS_CCNT + nbr[2*p], 1);
  }
}

__global__ __launch_bounds__(1024) void k_scan(float* ws){
  __shared__ int part[1024];
  int t = threadIdx.x;
  const int* cnt = (const int*)ws + WS_CCNT;
  int v0 = cnt[4*t], v1 = cnt[4*t+1], v2 = cnt[4*t+2], v3 = cnt[4*t+3];
  part[t] = v0+v1+v2+v3;
  __syncthreads();
  for(int o=1; o<1024; o<<=1){
    int x = (t >= o) ? part[t-o] : 0;
    __syncthreads();
    part[t] += x;
    __syncthreads();
  }
  int base = (t > 0) ? part[t-1] : 0;
  int* offp = (int*)ws + WS_COFF;
  int* cur  = (int*)ws + WS_CCUR;
  offp[4*t]   = base;          cur[4*t]   = base;
  offp[4*t+1] = base+v0;       cur[4*t+1] = base+v0;
  offp[4*t+2] = base+v0+v1;    cur[4*t+2] = base+v0+v1;
  offp[4*t+3] = base+v0+v1+v2; cur[4*t+3] = base+v0+v1+v2;
  if(t == 1023) offp[4096] = part[1023];
}

// ---------------- u2: {Gaunt lists (block 0) | fused fill+pair} ------------
__global__ __launch_bounds__(256) void k_u2(const float* disp, const int* nbr, float* ws){
  __shared__ float Gsh[5632];
  __shared__ int cA[25], cT[9], cA9[25], oA[26], oT[10], oA9[26];
  if(blockIdx.x == 0){
    int t = threadIdx.x;
    for(int i=t; i<5625; i+=256) Gsh[i] = ws[WS_G + i];
    __syncthreads();
    const float* G = Gsh;
    if(t < 25){
      int c=0, c9=0;
      for(int i=0;i<25;i++) for(int j=0;j<9;j++) if(G[(i*9+j)*25+t] != 0.f){ c++; if(i<9) c9++; }
      cA[t]=c; cA9[t]=c9;
    }
    if(t < 9){ int c=0; for(int i=0;i<9;i++) for(int j=0;j<9;j++) if(G[(i*9+j)*25+t] != 0.f) c++; cT[t]=c; }
    __syncthreads();
    if(t == 0){
      int s=0; for(int k=0;k<25;k++){ oA[k]=s; s+=cA[k]; } oA[25]=s;
      ((int*)ws)[WS_NATT] = s;
      s=0; for(int k=0;k<25;k++){ oA9[k]=s; s+=cA9[k]; } oA9[25]=s;
      s=0; for(int k=0;k<9;k++){ oT[k]=s; s+=cT[k]; } oT[9]=s;
    }
    __syncthreads();
    float* attw = ws + WS_ATTW;  int* attij = (int*)ws + WS_ATTIJ;
    float* attw9 = ws + WS_ATTW9; int* attij9 = (int*)ws + WS_ATTIJ9;
    int* aofs  = (int*)ws + WS_AOFS;
    int* aofs9 = (int*)ws + WS_AOFS9;
    if(t < 26){ aofs[t] = oA[t] < 1024 ? oA[t] : 1024; aofs9[t] = oA9[t] < 512 ? oA9[t] : 512; }
    if(t < 25){
      int pos = oA[t], pos9 = oA9[t];
      for(int i=0;i<25;i++) for(int j=0;j<9;j++){
        float w = G[(i*9+j)*25+t];
        if(w != 0.f){
          if(pos < 1024){ attw[pos]=w; attij[pos] = i | (j<<5) | (t<<9); pos++; }
          if(i < 9 && pos9 < 512){ attw9[pos9]=w; attij9[pos9] = i | (j<<5) | (t<<9); pos9++; }
        }
      }
    }
    float* tdw = ws + WS_TDW; int* tdij = (int*)ws + WS_TDIJ; int* tdofs = (int*)ws + WS_TDOFS;
    if(t < 9){
      int pos = oT[t];
      for(int i=0;i<9;i++) for(int j=0;j<9;j++){
        float w = G[(i*9+j)*25+t];
        if(w != 0.f && pos < 512){
          int li = (i==0)?0:(i<4)?1:2, lj = (j==0)?0:(j<4)?1:2;
          tdw[pos]=w; tdij[pos] = i | (j<<5) | (li<<10) | (lj<<12); pos++;
        }
      }
      tdofs[t] = oT[t];
      if(t == 0) tdofs[9] = oT[9];
    }
  } else {
    int p = (blockIdx.x-1)*256 + threadIdx.x;
    if(p >= NP) return;
    int d = nbr[2*p], s = nbr[2*p+1];
    int sp = atomicAdd((int*)ws + WS_CCUR + d, 1);
    ((int*)ws)[WS_DS + 2*sp]     = d;
    ((int*)ws)[WS_DS + 2*sp + 1] = s;
    float dx = disp[3*p], dy = disp[3*p+1], dz = disp[3*p+2];
    float r = sqrtf(dx*dx + dy*dy + dz*dz);
    float inv = 1.f / fmaxf(r, 1e-9f);
    float ux = dx*inv, uy = dy*inv, uz = dz*inv;
    float sh[9];
    sh[0] = 0.28209479177387814f;
    sh[1] = 0.4886025119029199f * uy;
    sh[2] = 0.4886025119029199f * uz;
    sh[3] = 0.4886025119029199f * ux;
    sh[4] = 1.0925484305920792f * ux*uy;
    sh[5] = 1.0925484305920792f * uy*uz;
    sh[6] = 0.31539156525252005f * (3.f*uz*uz - 1.f);
    sh[7] = 1.0925484305920792f * ux*uz;
    sh[8] = 0.5462742152960396f * (ux*ux - uy*uy);
    #pragma unroll
    for(int i=0;i<9;i++) ws[WS_SH + sp*9 + i] = scrub(sh[i]);
    float mask = (r < 5.f) ? 1.f : 0.f;
    float rbv[16];
    #pragma unroll
    for(int k=1;k<=16;k++){
      float x  = (float)k * r * 0.2f;
      float px = 3.14159265358979323846f * x;
      float s2 = (px < 1e-6f) ? 1.f : (sinf(px)/px);
      rbv[k-1] = scrub(s2 * mask);
    }
    float4* rb4 = (float4*)(ws + WS_RB + sp*16);
    #pragma unroll
    for(int c=0;c<4;c++) rb4[c] = make_float4(rbv[4*c], rbv[4*c+1], rbv[4*c+2], rbv[4*c+3]);
  }
}

// ---------------- TD phase (sorted-index reads) ----------------
__global__ __launch_bounds__(256) void k_td(const int* aZ, const float* W3, float* ws){
  __shared__ float sh_s[16][9];
  __shared__ float S_s[16][88];
  __shared__ float tp_s[16][9][16];
  int tid = threadIdx.x, pl = tid >> 4, g = tid & 15;
  int sp = blockIdx.x*16 + pl;
  int src = ((const int*)ws)[WS_DS + 2*sp + 1];
  int Zj = aZ[src];
  {
    float4* S4 = (float4*)&S_s[0][0];
    for(int t0=tid; t0<352; t0+=256) S4[t0] = make_float4(0.f,0.f,0.f,0.f);
  }
  if(g < 9) sh_s[pl][g] = ws[WS_SH + sp*9 + g];
  float rb[16];
  {
    const float4* rb4 = (const float4*)(ws + WS_RB + sp*16);
    #pragma unroll
    for(int c=0;c<4;c++){
      float4 r = rb4[c];
      rb[4*c]=r.x; rb[4*c+1]=r.y; rb[4*c+2]=r.z; rb[4*c+3]=r.w;
    }
  }
  float A1[3], A2[3];
  {
    const float4* w1 = (const float4*)(ws + WS_WW + ((size_t)(Zj*2+0)*16+g)*48);
    const float4* w2 = (const float4*)(ws + WS_WW + ((size_t)(Zj*2+1)*16+g)*48);
    #pragma unroll
    for(int d=0; d<3; d++){
      float a1 = 0.f, a2 = 0.f;
      #pragma unroll
      for(int c=0;c<4;c++){
        float4 x1 = w1[d*4+c], x2 = w2[d*4+c];
        a1 += x1.x*rb[4*c] + x1.y*rb[4*c+1] + x1.z*rb[4*c+2] + x1.w*rb[4*c+3];
        a2 += x2.x*rb[4*c] + x2.y*rb[4*c+1] + x2.z*rb[4*c+2] + x2.w*rb[4*c+3];
      }
      A1[d] = a1; A2[d] = a2;
    }
  }
  __syncthreads();
  if(g < 9){
    const float* tdw = ws + WS_TDW;
    const int* tdij  = (const int*)ws + WS_TDIJ;
    const int* tdofs = (const int*)ws + WS_TDOFS;
    int e1 = tdofs[g+1];
    for(int e=tdofs[g]; e<e1; e++){
      float w = tdw[e]; int meta = tdij[e];
      int i = meta & 31, j = (meta>>5) & 15, li = (meta>>10) & 3, lj = (meta>>12) & 3;
      S_s[pl][g*9 + li*3 + lj] += w * sh_s[pl][i] * sh_s[pl][j];
    }
  }
  __syncthreads();
  float AA[9];
  #pragma unroll
  for(int li=0;li<3;li++)
    #pragma unroll
    for(int lj=0;lj<3;lj++) AA[li*3+lj] = A1[li]*A2[lj];
  #pragma unroll
  for(int k=0;k<9;k++){
    float tpv = 0.f;
    #pragma unroll
    for(int c=0;c<9;c++) tpv += S_s[pl][k*9+c] * AA[c];
    tp_s[pl][k][g] = tpv;
  }
  __syncthreads();
  float w3r[48];
  #pragma unroll
  for(int d=0;d<3;d++)
    #pragma unroll
    for(int f2=0;f2<16;f2++) w3r[d*16+f2] = W3[(d*16+f2)*16+g];
  float acc9[9];
  #pragma unroll
  for(int k=0;k<9;k++){
    int d = (k==0)?0:(k<4)?1:2;
    const float4* t4 = (const float4*)&tp_s[pl][k][0];
    float acc = 0.f;
    #pragma unroll
    for(int c=0;c<4;c++){
      float4 t = t4[c];
      acc += t.x*w3r[d*16+4*c] + t.y*w3r[d*16+4*c+1] + t.z*w3r[d*16+4*c+2] + t.w*w3r[d*16+4*c+3];
    }
    acc9[k] = scrub(acc);
  }
  f16* ptd = (f16*)(ws + WS_PVF) + (size_t)sp*256 + g*16;
  U4H u0, u1;
  #pragma unroll
  for(int j=0;j<8;j++) u0.h[j] = (f16)acc9[j];
  u1.h[0] = (f16)acc9[8];
  #pragma unroll
  for(int j=1;j<8;j++) u1.h[j] = (f16)0.f;
  *(uint4*)(ptd)     = u0.u;
  *(uint4*)(ptd + 8) = u1.u;
}

// ---------------- fused TD gather + layer-1 QKV (NL=3) ----------------
__global__ __launch_bounds__(256) void k_tdq(const float* Wq, const float* Wk,
                                             const float* Wv, float* ws){
  __shared__ float xsh[4][144];
  __shared__ float wq_sh[768], wk_sh[768], wv_sh[768];
  int tid = threadIdx.x, al = tid >> 6, lane = tid & 63;
  int a = blockIdx.x*4 + al;
  for(int t=tid; t<768; t+=256){ wq_sh[t]=Wq[t]; wk_sh[t]=Wk[t]; wv_sh[t]=Wv[t]; }
  const int* coff = (const int*)ws + WS_COFF;
  int off0 = coff[a], n = coff[a+1] - off0;
  const f16* base = (const f16*)(ws + WS_PVF);
  float acc[8] = {0,0,0,0,0,0,0,0};
  if(lane < 32){
    for(int t=0; t<n; t++){
      U4H u; u.u = *(const uint4*)(base + (size_t)(off0+t)*256 + lane*8);
      #pragma unroll
      for(int j=0;j<8;j++) acc[j] += (float)u.h[j];
    }
  }
  float invn = 1.f / fmaxf((float)n, 1.f);
  if(lane < 32){
    int gg = lane >> 1;
    #pragma unroll
    for(int j=0;j<8;j++){
      int k = (lane & 1)*8 + j;
      if(k < 9) xsh[al][k*16 + gg] = scrub(acc[j]*invn);
    }
  }
  __syncthreads();
  int g = lane & 15, q4 = lane >> 4;
  f16* qt = (f16*)(ws + WS_XQ) + (size_t)a*800 + g*32;
  f16* kt = (f16*)(ws + WS_XK) + (size_t)a*800 + g*32;
  f16* vt = (f16*)(ws + WS_XV) + (size_t)a*800 + g*32;
  for(int i=q4; i<9; i+=4){
    int l = (i==0)?0:(i<4)?1:2;
    float q=0.f, k2=0.f, v2=0.f;
    #pragma unroll
    for(int f2=0;f2<16;f2++){
      float xv = xsh[al][i*16+f2];
      q  += xv*wq_sh[(l*16+f2)*16+g];
      k2 += xv*wk_sh[(l*16+f2)*16+g];
      v2 += xv*wv_sh[(l*16+f2)*16+g];
    }
    qt[i] = (f16)q; kt[i] = (f16)k2; vt[i] = (f16)v2;
  }
}

// ---------------- merged attention (dual-chain fdot2 sweep) ----------------
template<int NI>
__global__ __launch_bounds__(128) void k_att(const float* Wb, float* ws){
  constexpr int MROWH = (NI == 9) ? 16 : 32;
  constexpr int PLSTR = (NI == 9) ? 408 : 840;
  __shared__ __align__(16) f16 Ml[8][PLSTR];
  __shared__ float sh_s[8][9];
  __shared__ float wb_sh[256];
  constexpr int NPAIR = NI/2;
  constexpr int TAIL  = NI-1;
  int tid = threadIdx.x, pl = tid >> 4, g = tid & 15;
  int sp = blockIdx.x*8 + pl;
  {
    uint4 z; z.x=0; z.y=0; z.z=0; z.w=0;
    uint4* Mz = (uint4*)&Ml[0][0];
    for(int t0=tid; t0<PLSTR; t0+=128) Mz[t0] = z;
  }
  for(int t0=tid; t0<256; t0+=128) wb_sh[t0] = Wb[t0];
  if(g < 9) sh_s[pl][g] = ws[WS_SH + sp*9 + g];
  __syncthreads();
  {
    const float* attw = ws + (NI==9 ? WS_ATTW9 : WS_ATTW);
    const int* attij  = (const int*)ws + (NI==9 ? WS_ATTIJ9 : WS_ATTIJ);
    const int* aofs   = (const int*)ws + (NI==9 ? WS_AOFS9 : WS_AOFS);
    for(int kr=g; kr<25; kr+=16){
      f16* Mrow = &Ml[pl][kr*MROWH];
      int e = aofs[kr], e1 = aofs[kr+1];
      if(e < e1){
        int meta = attij[e];
        int curi = meta & 31;
        float cur = 0.f;
        for(; e<e1; e++){
          meta = attij[e];
          int i2 = meta & 31;
          if(i2 != curi){ Mrow[curi] = (f16)cur; cur = 0.f; curi = i2; }
          cur += attw[e] * sh_s[pl][(meta>>5) & 15];
        }
        Mrow[curi] = (f16)cur;
      }
    }
  }
  __syncthreads();
  int dst = ((const int*)ws)[WS_DS + 2*sp];
  int src = ((const int*)ws)[WS_DS + 2*sp + 1];
  float q_r[NI];
  {
    const f16* qt = (const f16*)(ws + WS_XQ) + (size_t)dst*800 + g*32;
    #pragma unroll
    for(int c=0;c<NPAIR/4;c++){
      U4H u; u.u = *(const uint4*)(qt + c*8);
      #pragma unroll
      for(int j=0;j<8;j++) q_r[c*8+j] = (float)u.h[j];
    }
    q_r[TAIL] = (float)qt[TAIL];
  }
  h2 xk2[NPAIR], xv2[NPAIR];
  float xkT, xvT;
  {
    const f16* kt = (const f16*)(ws + WS_XK) + (size_t)src*800 + g*32;
    const f16* vt = (const f16*)(ws + WS_XV) + (size_t)src*800 + g*32;
    #pragma unroll
    for(int c=0;c<NPAIR/4;c++){
      U4H uk; uk.u = *(const uint4*)(kt + c*8);
      U4H uv; uv.u = *(const uint4*)(vt + c*8);
      #pragma unroll
      for(int j=0;j<4;j++){ xk2[c*4+j] = uk.p[j]; xv2[c*4+j] = uv.p[j]; }
    }
    xkT = (float)kt[TAIL];
    xvT = (float)vt[TAIL];
  }
  float wbf;
  {
    const float4* rb4 = (const float4*)(ws + WS_RB + sp*16);
    float acc = 0.f;
    #pragma unroll
    for(int c=0;c<4;c++){
      float4 r = rb4[c];
      acc += r.x*wb_sh[(4*c)*16+g] + r.y*wb_sh[(4*c+1)*16+g]
           + r.z*wb_sh[(4*c+2)*16+g] + r.w*wb_sh[(4*c+3)*16+g];
    }
    wbf = acc;
  }
  f16* pvf = (f16*)(ws + WS_PVF) + (size_t)sp*400;
  float sacc = 0.f;
  #pragma unroll
  for(int k=0;k<25;k++){
    const uint4* Mq = (const uint4*)&Ml[pl][k*MROWH];
    float mT = (float)Ml[pl][k*MROWH + TAIL];
    float vv0 = 0.f, vv1 = 0.f, kf0 = 0.f, kf1 = 0.f;
    #pragma unroll
    for(int c=0;c<NPAIR/4;c++){
      U4H u; u.u = Mq[c];
      vv0 = fdot2(u.p[0], xv2[c*4+0], vv0);
      vv1 = fdot2(u.p[1], xv2[c*4+1], vv1);
      vv0 = fdot2(u.p[2], xv2[c*4+2], vv0);
      vv1 = fdot2(u.p[3], xv2[c*4+3], vv1);
      if(k < NI){
        kf0 = fdot2(u.p[0], xk2[c*4+0], kf0);
        kf1 = fdot2(u.p[1], xk2[c*4+1], kf1);
        kf0 = fdot2(u.p[2], xk2[c*4+2], kf0);
        kf1 = fdot2(u.p[3], xk2[c*4+3], kf1);
      }
    }
    float vv = vv0 + vv1 + mT*xvT;
    if(k < NI){
      float kf = kf0 + kf1 + mT*xkT;
      sacc += q_r[k]*kf;
    }
    pvf[k*16 + g] = (f16)scrub(wbf*vv);
  }
  float sl = sacc;
  #pragma unroll
  for(int off=1; off<16; off<<=1) sl += __shfl_xor(sl, off, 16);
  if(g == 0) ws[WS_S + sp] = scrub(sl * 0.05f);   // / sqrt(25*16)
}

// ---------------- fused softmax-gather + output pdense (+QKV next / final) -
template<bool FINAL>
__global__ __launch_bounds__(256) void k_aggo(const float* Wo, const float* bo,
    const int* aZ, const float* emb, const float* Wemb, const float* bemb,
    const float* Wq, const float* Wk, const float* Wv, float* ws, float* out){
  __shared__ float xsh[4][400];
  __shared__ float wo_sh[1280];
  __shared__ float wq_sh[FINAL?4:1280], wk_sh[FINAL?4:1280], wv_sh[FINAL?4:1280];
  __shared__ float osh[FINAL?4:1600];
  int tid = threadIdx.x, al = tid >> 6, lane = tid & 63;
  int a = blockIdx.x*4 + al;
  for(int t=tid; t<1280; t+=256){
    wo_sh[t] = Wo[t];
    if(!FINAL){ wq_sh[t]=Wq[t]; wk_sh[t]=Wk[t]; wv_sh[t]=Wv[t]; }
  }
  const int* coff = (const int*)ws + WS_COFF;
  int off0 = coff[a], n = coff[a+1] - off0;
  float mx = -1e30f;
  for(int t=lane; t<n; t+=64) mx = fmaxf(mx, ws[WS_S + off0 + t]);
  #pragma unroll
  for(int off=1; off<64; off<<=1) mx = fmaxf(mx, __shfl_xor(mx, off));
  float den = 0.f;
  for(int t=lane; t<n; t+=64) den += expf(fminf(ws[WS_S + off0 + t] - mx, 0.f));
  #pragma unroll
  for(int off=1; off<64; off<<=1) den += __shfl_xor(den, off);
  float inv_den = 1.f / (den + 1e-9f);
  float acc[8] = {0,0,0,0,0,0,0,0};
  const f16* base = (const f16*)(ws + WS_PVF);
  for(int t=0; t<n; t++){
    float alpha = expf(fminf(ws[WS_S + off0 + t] - mx, 0.f)) * inv_den;
    if(lane < 50){
      U4H u; u.u = *(const uint4*)(base + (size_t)(off0+t)*400 + lane*8);
      #pragma unroll
      for(int j=0;j<8;j++) acc[j] += alpha * (float)u.h[j];
    }
  }
  if(lane < 50){
    #pragma unroll
    for(int j=0;j<8;j++) xsh[al][lane*8 + j] = scrub(acc[j]);   // flat = k*16+g
  }
  __syncthreads();
  int g = lane & 15, q4 = lane >> 4;
  for(int i=q4; i<25; i+=4){
    int l = (i==0)?0:(i<4)?1:(i<9)?2:(i<16)?3:4;
    float accv = 0.f;
    #pragma unroll
    for(int f2=0;f2<16;f2++) accv += xsh[al][i*16+f2]*wo_sh[(l*16+f2)*16+g];
    if(i == 0){
      accv += bo[g];
      if(FINAL){
        int Z = aZ[a];
        float res = bemb[g];
        #pragma unroll
        for(int e2=0;e2<32;e2++) res += emb[Z*32+e2]*Wemb[e2*16+g];
        accv += res;
      }
    }
    if(FINAL) out[a*400 + i*16 + g] = scrub(accv);
    else      osh[al*400 + i*16 + g] = scrub(accv);
  }
  if(!FINAL){
    __syncthreads();
    f16* qt = (f16*)(ws + WS_XQ) + (size_t)a*800 + g*32;
    f16* kt = (f16*)(ws + WS_XK) + (size_t)a*800 + g*32;
    f16* vt = (f16*)(ws + WS_XV) + (size_t)a*800 + g*32;
    for(int i=q4; i<25; i+=4){
      int l = (i==0)?0:(i<4)?1:(i<9)?2:(i<16)?3:4;
      float q=0.f, k2=0.f, v2=0.f;
      #pragma unroll
      for(int f2=0;f2<16;f2++){
        float xv = osh[al*400 + i*16 + f2];
        q  += xv*wq_sh[(l*16+f2)*16+g];
        k2 += xv*wk_sh[(l*16+f2)*16+g];
        v2 += xv*wv_sh[(l*16+f2)*16+g];
      }
      qt[i] = (f16)q; kt[i] = (f16)k2; vt[i] = (f16)v2;
    }
  }
}

extern "C" void kernel_launch(void* const* d_in, const int* in_sizes, int n_in,
                              void* d_out, int out_size, void* d_ws, size_t ws_size,
                              hipStream_t stream){
  (void)in_sizes; (void)n_in; (void)out_size;
  if(ws_size < (size_t)WS_END * sizeof(float)) return;
  float* ws = (float*)d_ws;
  const int* aZ  = (const int*)d_in[0];
  const int* nbr = (const int*)d_in[1];
  const float* disp = (const float*)d_in[2];
  const float* Wrad = (const float*)d_in[3];
  const float* emb  = (const float*)d_in[4];
  const float* Wemb = (const float*)d_in[5];
  const float* bemb = (const float*)d_in[6];
  const float* W1   = (const float*)d_in[7];
  const float* W2   = (const float*)d_in[8];
  const float* W3   = (const float*)d_in[9];
  const float* Wb1 = (const float*)d_in[10]; const float* Wq1 = (const float*)d_in[11];
  const float* Wk1 = (const float*)d_in[12]; const float* Wv1 = (const float*)d_in[13];
  const float* Wo1 = (const float*)d_in[14]; const float* bo1 = (const float*)d_in[15];
  const float* Wb2 = (const float*)d_in[16]; const float* Wq2 = (const float*)d_in[17];
  const float* Wk2 = (const float*)d_in[18]; const float* Wv2 = (const float*)d_in[19];
  const float* Wo2 = (const float*)d_in[20]; const float* bo2 = (const float*)d_in[21];

  hipMemsetAsync(ws + WS_CCNT, 0, NA*sizeof(int), stream);
  k_u1<<<463,256,0,stream>>>(Wrad, W1, W2, nbr, ws);     // G | WW | CSR-count
  k_scan<<<1,1024,0,stream>>>(ws);
  k_u2<<<193,256,0,stream>>>(disp, nbr, ws);             // lists | fill+pair
  k_td<<<3072,256,0,stream>>>(aZ, W3, ws);
  k_tdq<<<1024,256,0,stream>>>(Wq1, Wk1, Wv1, ws);

  k_att<9><<<6144,128,0,stream>>>(Wb1, ws);
  k_aggo<false><<<1024,256,0,stream>>>(Wo1, bo1, aZ, emb, Wemb, bemb,
                                       Wq2, Wk2, Wv2, ws, nullptr);
  k_att<25><<<6144,128,0,stream>>>(Wb2, ws);
  k_aggo<true><<<1024,256,0,stream>>>(Wo2, bo2, aZ, emb, Wemb, bemb,
                                      nullptr, nullptr, nullptr, ws, (float*)d_out);
}